// Round 7
// baseline (13937.428 us; speedup 1.0000x reference)
//
#include <hip/hip_runtime.h>

// ---------------- problem constants ----------------
#define B_ 2
#define T_ 1024
#define C_ 768
#define H_ 12
#define L_ 6
#define V_ 32000
#define HS_ 64
#define M_ (B_*T_)            // 2048 token rows
#define C4_ (4*C_)            // 3072

// ---------------- embedding: x = tok_emb[idx] + pos_emb (fp32, idx int32) ----------------
__global__ __launch_bounds__(256) void embed_kernel(const int* __restrict__ idx,
                                                    const float* __restrict__ tok,
                                                    const float* __restrict__ pos,
                                                    float* __restrict__ x) {
  int m = blockIdx.x;                 // 0..M_-1
  int t = m & (T_ - 1);
  int tk = idx[m];
  #pragma unroll
  for (int i = 0; i < 3; ++i) {
    int c = threadIdx.x + i * 256;
    x[(size_t)m * C_ + c] = tok[(size_t)tk * C_ + c] + pos[(size_t)t * C_ + c];
  }
}

// ---------------- layernorm: h = LN(x)*g + b (all fp32) ----------------
__global__ __launch_bounds__(256) void ln_kernel(const float* __restrict__ x,
                                                 const float* __restrict__ g,
                                                 const float* __restrict__ bta,
                                                 float* __restrict__ h) {
  int m = blockIdx.x;
  const float* xr = x + (size_t)m * C_;
  float v[3], s = 0.f, ss = 0.f;
  #pragma unroll
  for (int i = 0; i < 3; ++i) {
    v[i] = xr[threadIdx.x + i * 256];
    s += v[i]; ss += v[i] * v[i];
  }
  #pragma unroll
  for (int off = 32; off; off >>= 1) { s += __shfl_xor(s, off); ss += __shfl_xor(ss, off); }
  __shared__ float red[8];
  int wave = threadIdx.x >> 6, lane = threadIdx.x & 63;
  if (lane == 0) { red[wave] = s; red[4 + wave] = ss; }
  __syncthreads();
  s  = red[0] + red[1] + red[2] + red[3];
  ss = red[4] + red[5] + red[6] + red[7];
  float mean = s * (1.f / C_);
  float var  = fmaxf(ss * (1.f / C_) - mean * mean, 0.f);
  float rstd = rsqrtf(var + 1e-5f);
  #pragma unroll
  for (int i = 0; i < 3; ++i) {
    int c = threadIdx.x + i * 256;
    h[(size_t)m * C_ + c] = (v[i] - mean) * rstd * g[c] + bta[c];
  }
}

// ---------------- naive two-pass attention (1 wave-block = 1 query row, fp32) ----------------
__global__ __launch_bounds__(64) void attn_naive(const float* __restrict__ q,
                                                 const float* __restrict__ k,
                                                 const float* __restrict__ v,
                                                 float* __restrict__ o) {
  const float scale = 0.03608439182435161f;   // 768^-0.5 (reference scales by C, not HS)
  __shared__ float ld[64][65];
  int l = threadIdx.x;
  int gr = blockIdx.x;                 // (b*H + h)*T + t
  int t  = gr & (T_ - 1);
  int bh = gr >> 10;
  int hh = bh % H_, bb = bh / H_;
  size_t base = (size_t)bb * T_ * C_ + (size_t)hh * HS_;
  float qv = q[base + (size_t)t * C_ + l] * scale;
  int nj = (t >> 6) + 1;               // K/V tiles covering [0, t]

  float sc[16];
  float mx = -INFINITY;
  #pragma unroll
  for (int j = 0; j < 16; ++j) {
    sc[j] = -INFINITY;
    if (j >= nj) continue;             // wave-uniform
    #pragma unroll 8
    for (int r = 0; r < 64; ++r)
      ld[r][l] = k[base + (size_t)(j * 64 + r) * C_ + l];
    __syncthreads();
    int u = j * 64 + l;
    float s = 0.f;
    #pragma unroll 8
    for (int ssx = 0; ssx < 64; ++ssx)
      s += __shfl(qv, ssx) * ld[l][ssx];
    if (u <= t) { sc[j] = s; mx = fmaxf(mx, s); }
    __syncthreads();
  }
  #pragma unroll
  for (int off = 32; off; off >>= 1) mx = fmaxf(mx, __shfl_xor(mx, off));

  float den = 0.f;
  #pragma unroll
  for (int j = 0; j < 16; ++j) {
    float w = (sc[j] == -INFINITY) ? 0.f : __expf(sc[j] - mx);
    sc[j] = w;
    den += w;
  }
  #pragma unroll
  for (int off = 32; off; off >>= 1) den += __shfl_xor(den, off);

  float acc = 0.f;
  #pragma unroll
  for (int j = 0; j < 16; ++j) {
    if (j >= nj) continue;             // wave-uniform
    #pragma unroll 8
    for (int r = 0; r < 64; ++r)
      ld[r][l] = v[base + (size_t)(j * 64 + r) * C_ + l];
    __syncthreads();
    int rmax = t - j * 64; if (rmax > 63) rmax = 63;
    for (int r = 0; r <= rmax; ++r)
      acc += __shfl(sc[j], r) * ld[r][l];
    __syncthreads();
  }
  o[base + (size_t)t * C_ + l] = acc / den;
}

// ---------------- NN GEMM: out[M, zOcol*z + N] = A[M,K] * B[K,N] (+fp32 bias) ----------------
// B in natural [K][N] layout (row stride ldB). z-batched for QKV heads.
// EPI: 0 = store f32, 1 = store relu f32, 2 = residual += f32
template<int EPI>
__global__ __launch_bounds__(256) void gemm_nn(const float* __restrict__ A,
                                               const float* __restrict__ Bw,
                                               const float* __restrict__ bias,
                                               float* __restrict__ outf,
                                               int M, int N, int K, int ldB, int ldO,
                                               size_t zB, int zOcol) {
  __shared__ float As[64][17];
  __shared__ float Bs[16][65];
  int tid = threadIdx.x;
  int ty = tid >> 4, tx = tid & 15;            // 16x16 threads, 4x4 outputs each
  int m0 = blockIdx.y * 64, n0 = blockIdx.x * 64;
  const float* Bp = Bw + zB * blockIdx.z;
  int cbase = zOcol * blockIdx.z + n0;         // global output column base
  float acc[4][4] = {};

  for (int k0 = 0; k0 < K; k0 += 16) {
    #pragma unroll
    for (int e = tid; e < 1024; e += 256) {    // A tile: 64 m x 16 k
      int r = e >> 4, c = e & 15;
      As[r][c] = A[(size_t)(m0 + r) * K + k0 + c];
    }
    #pragma unroll
    for (int e = tid; e < 1024; e += 256) {    // B tile: 16 k x 64 n
      int kk = e >> 6, nn = e & 63;
      Bs[kk][nn] = Bp[(size_t)(k0 + kk) * ldB + n0 + nn];
    }
    __syncthreads();
    #pragma unroll
    for (int kk = 0; kk < 16; ++kk) {
      float a[4], b[4];
      #pragma unroll
      for (int i = 0; i < 4; ++i) a[i] = As[ty * 4 + i][kk];
      #pragma unroll
      for (int j = 0; j < 4; ++j) b[j] = Bs[kk][tx * 4 + j];
      #pragma unroll
      for (int i = 0; i < 4; ++i)
        #pragma unroll
        for (int j = 0; j < 4; ++j)
          acc[i][j] = fmaf(a[i], b[j], acc[i][j]);
    }
    __syncthreads();
  }

  #pragma unroll
  for (int i = 0; i < 4; ++i) {
    #pragma unroll
    for (int j = 0; j < 4; ++j) {
      int m = m0 + ty * 4 + i, n = cbase + tx * 4 + j;
      float val = acc[i][j];
      if (bias) val += bias[n];
      if (EPI == 0)      outf[(size_t)m * ldO + n] = val;
      else if (EPI == 1) outf[(size_t)m * ldO + n] = fmaxf(val, 0.f);
      else               outf[(size_t)m * ldO + n] += val;
    }
  }
}

// ---------------- host-side launch ----------------
extern "C" void kernel_launch(void* const* d_in, const int* in_sizes, int n_in,
                              void* d_out, int out_size, void* d_ws, size_t ws_size,
                              hipStream_t stream) {
  const int*   idx  = (const int*)d_in[0];
  const float* tok  = (const float*)d_in[1];
  const float* pos  = (const float*)d_in[2];
  const float* Wq   = (const float*)d_in[3];
  const float* Wk   = (const float*)d_in[4];
  const float* Wv   = (const float*)d_in[5];
  const float* Wp   = (const float*)d_in[6];
  const float* bp   = (const float*)d_in[7];
  const float* ln1g = (const float*)d_in[8];
  const float* ln1b = (const float*)d_in[9];
  const float* ln2g = (const float*)d_in[10];
  const float* ln2b = (const float*)d_in[11];
  const float* W1   = (const float*)d_in[12];
  const float* b1   = (const float*)d_in[13];
  const float* W2   = (const float*)d_in[14];
  const float* b2   = (const float*)d_in[15];
  const float* lnfg = (const float*)d_in[16];
  const float* lnfb = (const float*)d_in[17];
  const float* Wh   = (const float*)d_in[18];
  const float* bh   = (const float*)d_in[19];

  float* out = (float*)d_out;   // reference output dtype is float32

  // ---- workspace: x + h + region(qkvo | mid) = 6*MC floats = 37.75 MB ----
  const size_t MC = (size_t)M_ * C_;
  if (ws_size < MC * 4 * 6) return;

  float* x      = (float*)d_ws;
  float* h      = x + MC;
  float* region = h + MC;
  float* qb  = region;              // [M][C] each
  float* kb  = region + MC;
  float* vb  = region + 2 * MC;
  float* ob  = region + 3 * MC;
  float* mid = region;              // [M][C4], time-shared with qkvo

  // ---- embedding ----
  embed_kernel<<<M_, 256, 0, stream>>>(idx, tok, pos, x);

  // ---- transformer blocks ----
  for (int l = 0; l < L_; ++l) {
    size_t wo  = (size_t)l * C_ * C_;
    size_t wo4 = (size_t)l * C_ * C4_;
    size_t woq = (size_t)l * H_ * C_ * HS_;

    ln_kernel<<<M_, 256, 0, stream>>>(x, ln1g + (size_t)l * C_, ln1b + (size_t)l * C_, h);
    // QKV: per-head z-batch. B_z = Wq[l,h] as [C][HS] (ldB=HS); out cols h*64.. of [M][C]
    gemm_nn<0><<<dim3(1, M_/64, H_), 256, 0, stream>>>(h, Wq + woq, nullptr, qb,
                                                       M_, HS_, C_, HS_, C_, (size_t)C_*HS_, HS_);
    gemm_nn<0><<<dim3(1, M_/64, H_), 256, 0, stream>>>(h, Wk + woq, nullptr, kb,
                                                       M_, HS_, C_, HS_, C_, (size_t)C_*HS_, HS_);
    gemm_nn<0><<<dim3(1, M_/64, H_), 256, 0, stream>>>(h, Wv + woq, nullptr, vb,
                                                       M_, HS_, C_, HS_, C_, (size_t)C_*HS_, HS_);
    attn_naive<<<B_*H_*T_, 64, 0, stream>>>(qb, kb, vb, ob);
    gemm_nn<2><<<dim3(C_/64, M_/64), 256, 0, stream>>>(ob, Wp + wo, bp + (size_t)l * C_, x,
                                                       M_, C_, C_, C_, C_, 0, 0);

    ln_kernel<<<M_, 256, 0, stream>>>(x, ln2g + (size_t)l * C_, ln2b + (size_t)l * C_, h);
    gemm_nn<1><<<dim3(C4_/64, M_/64), 256, 0, stream>>>(h, W1 + wo4, b1 + (size_t)l * C4_, mid,
                                                        M_, C4_, C_, C4_, C4_, 0, 0);
    gemm_nn<2><<<dim3(C_/64, M_/64), 256, 0, stream>>>(mid, W2 + wo4, b2 + (size_t)l * C_, x,
                                                       M_, C_, C4_, C_, C_, 0, 0);
  }

  // ---- final LN + lm_head (fp32 store straight to d_out) ----
  ln_kernel<<<M_, 256, 0, stream>>>(x, lnfg, lnfb, h);
  gemm_nn<0><<<dim3(V_/64, M_/64), 256, 0, stream>>>(h, Wh, bh, out,
                                                     M_, V_, C_, V_, V_, 0, 0);
}

// Round 8
// 5501.168 us; speedup vs baseline: 2.5335x; 2.5335x over previous
//
#include <hip/hip_runtime.h>

// ---------------- problem constants ----------------
#define B_ 2
#define T_ 1024
#define C_ 768
#define H_ 12
#define L_ 6
#define V_ 32000
#define HS_ 64
#define M_ (B_*T_)            // 2048 token rows
#define C4_ (4*C_)            // 3072
#define NVC_ 6400             // lm_head column chunk (5 chunks)

typedef __attribute__((ext_vector_type(8))) short short8;
typedef __attribute__((ext_vector_type(4))) float f32x4;

__device__ __forceinline__ float b2f(unsigned short u) {
  union { unsigned int i; float f; } x; x.i = ((unsigned int)u) << 16; return x.f;
}
__device__ __forceinline__ unsigned short f2b(float f) {
  unsigned int u = __builtin_bit_cast(unsigned int, f);
  u += 0x7fffu + ((u >> 16) & 1u);
  return (unsigned short)(u >> 16);
}

// -------- transpose + fp32->bf16: out[c][r] = bf16(in[r][c]), z-batched (VALIDATED r3/4) --------
__global__ __launch_bounds__(256) void transpose_f2b(const float* __restrict__ in,
                                                     unsigned short* __restrict__ out,
                                                     int ldi, int ldo, size_t zi, size_t zo) {
  __shared__ unsigned short tile[32][33];
  in  += zi * blockIdx.z;
  out += zo * blockIdx.z;
  int c0 = blockIdx.x * 32, r0 = blockIdx.y * 32;
  int tx = threadIdx.x & 31, ty = threadIdx.x >> 5;   // 32 x 8
  #pragma unroll
  for (int j = 0; j < 32; j += 8)
    tile[ty + j][tx] = f2b(in[(size_t)(r0 + ty + j) * ldi + c0 + tx]);
  __syncthreads();
  #pragma unroll
  for (int j = 0; j < 32; j += 8)
    out[(size_t)(c0 + ty + j) * ldo + r0 + tx] = tile[tx][ty + j];
}

// ---------------- embedding: x = tok_emb[idx] + pos_emb (fp32) ----------------
__global__ __launch_bounds__(256) void embed_kernel(const int* __restrict__ idx,
                                                    const float* __restrict__ tok,
                                                    const float* __restrict__ pos,
                                                    float* __restrict__ x) {
  int m = blockIdx.x;
  int t = m & (T_ - 1);
  int tk = idx[m];
  #pragma unroll
  for (int i = 0; i < 3; ++i) {
    int c = threadIdx.x + i * 256;
    x[(size_t)m * C_ + c] = tok[(size_t)tk * C_ + c] + pos[(size_t)t * C_ + c];
  }
}

// ---------------- layernorm: h(bf16) = LN(x)*g + b   (x,g,b fp32) ----------------
__global__ __launch_bounds__(256) void ln_kernel(const float* __restrict__ x,
                                                 const float* __restrict__ g,
                                                 const float* __restrict__ bta,
                                                 unsigned short* __restrict__ h) {
  int m = blockIdx.x;
  const float* xr = x + (size_t)m * C_;
  float v[3], s = 0.f, ss = 0.f;
  #pragma unroll
  for (int i = 0; i < 3; ++i) {
    v[i] = xr[threadIdx.x + i * 256];
    s += v[i]; ss += v[i] * v[i];
  }
  #pragma unroll
  for (int off = 32; off; off >>= 1) { s += __shfl_xor(s, off); ss += __shfl_xor(ss, off); }
  __shared__ float red[8];
  int wave = threadIdx.x >> 6, lane = threadIdx.x & 63;
  if (lane == 0) { red[wave] = s; red[4 + wave] = ss; }
  __syncthreads();
  s  = red[0] + red[1] + red[2] + red[3];
  ss = red[4] + red[5] + red[6] + red[7];
  float mean = s * (1.f / C_);
  float var  = fmaxf(ss * (1.f / C_) - mean * mean, 0.f);
  float rstd = rsqrtf(var + 1e-5f);
  #pragma unroll
  for (int i = 0; i < 3; ++i) {
    int c = threadIdx.x + i * 256;
    h[(size_t)m * C_ + c] = f2b((v[i] - mean) * rstd * g[c] + bta[c]);
  }
}

// ---------------- naive two-pass attention (fp32 q/k/v, bf16 o store) — VALIDATED r7 ----------------
__global__ __launch_bounds__(64) void attn_naive(const float* __restrict__ q,
                                                 const float* __restrict__ k,
                                                 const float* __restrict__ v,
                                                 unsigned short* __restrict__ o) {
  const float scale = 0.03608439182435161f;   // 768^-0.5 (reference scales by C, not HS)
  __shared__ float ld[64][65];
  int l = threadIdx.x;
  int gr = blockIdx.x;                 // (b*H + h)*T + t
  int t  = gr & (T_ - 1);
  int bh = gr >> 10;
  int hh = bh % H_, bb = bh / H_;
  size_t base = (size_t)bb * T_ * C_ + (size_t)hh * HS_;
  float qv = q[base + (size_t)t * C_ + l] * scale;
  int nj = (t >> 6) + 1;

  float sc[16];
  float mx = -INFINITY;
  #pragma unroll
  for (int j = 0; j < 16; ++j) {
    sc[j] = -INFINITY;
    if (j >= nj) continue;             // wave-uniform
    #pragma unroll 8
    for (int r = 0; r < 64; ++r)
      ld[r][l] = k[base + (size_t)(j * 64 + r) * C_ + l];
    __syncthreads();
    int u = j * 64 + l;
    float s = 0.f;
    #pragma unroll 8
    for (int ssx = 0; ssx < 64; ++ssx)
      s += __shfl(qv, ssx) * ld[l][ssx];
    if (u <= t) { sc[j] = s; mx = fmaxf(mx, s); }
    __syncthreads();
  }
  #pragma unroll
  for (int off = 32; off; off >>= 1) mx = fmaxf(mx, __shfl_xor(mx, off));

  float den = 0.f;
  #pragma unroll
  for (int j = 0; j < 16; ++j) {
    float w = (sc[j] == -INFINITY) ? 0.f : __expf(sc[j] - mx);
    sc[j] = w;
    den += w;
  }
  #pragma unroll
  for (int off = 32; off; off >>= 1) den += __shfl_xor(den, off);

  float acc = 0.f;
  #pragma unroll
  for (int j = 0; j < 16; ++j) {
    if (j >= nj) continue;             // wave-uniform
    #pragma unroll 8
    for (int r = 0; r < 64; ++r)
      ld[r][l] = v[base + (size_t)(j * 64 + r) * C_ + l];
    __syncthreads();
    int rmax = t - j * 64; if (rmax > 63) rmax = 63;
    for (int r = 0; r <= rmax; ++r)
      acc += __shfl(sc[j], r) * ld[r][l];
    __syncthreads();
  }
  o[base + (size_t)t * C_ + l] = f2b(acc / den);
}

// ------- MFMA BT GEMM: out[M,N] = A[M,K](bf16) * Bt[N,K]^T(bf16) (+fp32 bias) — VALIDATED r3/4 -------
// EPI: 0 = store bf16, 1 = relu bf16, 2 = fp32 residual +=, 3 = store fp32
template<int BM, int BN, int EPI>
__global__ __launch_bounds__(256) void gemm_bt(const unsigned short* __restrict__ A,
                                               const unsigned short* __restrict__ Bt,
                                               const float* __restrict__ bias,
                                               unsigned short* __restrict__ outb,
                                               float* __restrict__ outf,
                                               int M, int N, int K, int ldO) {
  constexpr int BK = 32;
  constexpr int LDT = BK + 8;   // 80B row stride: 16B-aligned, 2-way banks (free)
  __shared__ __align__(16) unsigned short As[BM * LDT];
  __shared__ __align__(16) unsigned short Bs[BN * LDT];
  constexpr int FM = BM / 32, FN = BN / 32;

  int tid = threadIdx.x;
  int lane = tid & 63, wave = tid >> 6;
  int wr = wave >> 1, wc = wave & 1;
  int m0 = blockIdx.y * BM, n0 = blockIdx.x * BN;
  int rl = lane & 15, koff = (lane >> 4) * 8;

  f32x4 acc[FM][FN] = {};

  for (int k0 = 0; k0 < K; k0 += BK) {
    #pragma unroll
    for (int e = tid; e < BM * 4; e += 256) {
      int row = e >> 2, c8 = e & 3;
      *(uint4*)&As[row * LDT + c8 * 8] =
          *(const uint4*)&A[(size_t)(m0 + row) * K + k0 + c8 * 8];
    }
    #pragma unroll
    for (int e = tid; e < BN * 4; e += 256) {
      int row = e >> 2, c8 = e & 3;
      *(uint4*)&Bs[row * LDT + c8 * 8] =
          *(const uint4*)&Bt[(size_t)(n0 + row) * K + k0 + c8 * 8];
    }
    __syncthreads();
    short8 af[FM], bfr[FN];
    #pragma unroll
    for (int i = 0; i < FM; ++i)
      af[i] = *(const short8*)&As[(wr * (BM / 2) + i * 16 + rl) * LDT + koff];
    #pragma unroll
    for (int j = 0; j < FN; ++j)
      bfr[j] = *(const short8*)&Bs[(wc * (BN / 2) + j * 16 + rl) * LDT + koff];
    #pragma unroll
    for (int i = 0; i < FM; ++i)
      #pragma unroll
      for (int j = 0; j < FN; ++j)
        acc[i][j] = __builtin_amdgcn_mfma_f32_16x16x32_bf16(af[i], bfr[j], acc[i][j], 0, 0, 0);
    __syncthreads();
  }

  int rbase = (lane >> 4) * 4;
  #pragma unroll
  for (int i = 0; i < FM; ++i) {
    #pragma unroll
    for (int j = 0; j < FN; ++j) {
      #pragma unroll
      for (int r = 0; r < 4; ++r) {
        int m = m0 + wr * (BM / 2) + i * 16 + rbase + r;
        int n = n0 + wc * (BN / 2) + j * 16 + (lane & 15);
        float val = acc[i][j][r];
        if (bias) val += bias[n];
        if (EPI == 0)      outb[(size_t)m * ldO + n] = f2b(val);
        else if (EPI == 1) outb[(size_t)m * ldO + n] = f2b(fmaxf(val, 0.f));
        else if (EPI == 2) outf[(size_t)m * ldO + n] += val;
        else               outf[(size_t)m * ldO + n] = val;
      }
    }
  }
}

// ---------------- host-side launch ----------------
extern "C" void kernel_launch(void* const* d_in, const int* in_sizes, int n_in,
                              void* d_out, int out_size, void* d_ws, size_t ws_size,
                              hipStream_t stream) {
  const int*   idx  = (const int*)d_in[0];
  const float* tok  = (const float*)d_in[1];
  const float* pos  = (const float*)d_in[2];
  const float* Wq   = (const float*)d_in[3];
  const float* Wk   = (const float*)d_in[4];
  const float* Wv   = (const float*)d_in[5];
  const float* Wp   = (const float*)d_in[6];
  const float* bp   = (const float*)d_in[7];
  const float* ln1g = (const float*)d_in[8];
  const float* ln1b = (const float*)d_in[9];
  const float* ln2g = (const float*)d_in[10];
  const float* ln2b = (const float*)d_in[11];
  const float* W1   = (const float*)d_in[12];
  const float* b1   = (const float*)d_in[13];
  const float* W2   = (const float*)d_in[14];
  const float* b2   = (const float*)d_in[15];
  const float* lnfg = (const float*)d_in[16];
  const float* lnfb = (const float*)d_in[17];
  const float* Wh   = (const float*)d_in[18];
  const float* bh   = (const float*)d_in[19];

  float* out = (float*)d_out;   // fp32 logits

  // ---- workspace plan: 41.3 MB (ws >= 44.5 MB proven in r3) ----
  const size_t MC = (size_t)M_ * C_;
  const size_t need = MC*4            // x fp32
                    + MC*2            // h bf16
                    + MC*4*3          // qf,kf,vf fp32 (attn stays fp32)
                    + MC*2            // o bf16
                    + (size_t)NVC_*C_*2;  // weight-transpose scratch (>= mid? no, mid overlays qf)
  if (ws_size < need) return;

  char* p = (char*)d_ws;
  float*          x   = (float*)p;            p += MC*4;
  unsigned short* h   = (unsigned short*)p;   p += MC*2;
  float*          qf  = (float*)p;            p += MC*4;
  float*          kf  = (float*)p;            p += MC*4;
  float*          vf  = (float*)p;            p += MC*4;
  unsigned short* o   = (unsigned short*)p;   p += MC*2;
  unsigned short* WT  = (unsigned short*)p;   p += (size_t)NVC_*C_*2;
  unsigned short* mid = (unsigned short*)qf;  // [M][C4] bf16 = 12.6MB, overlays qf/kf (dead)

  unsigned short* WqT = WT;                   // [768][768] bf16, row n = h*64+s
  unsigned short* WkT = WT + (size_t)C_*C_;
  unsigned short* WvT = WT + (size_t)2*C_*C_;
  unsigned short* WpT = WT + (size_t)3*C_*C_;
  unsigned short* W12T = WT;                  // [C4][C] or [C][C4], reused

  embed_kernel<<<M_, 256, 0, stream>>>(idx, tok, pos, x);

  for (int l = 0; l < L_; ++l) {
    size_t wo  = (size_t)l * C_ * C_;
    size_t wo4 = (size_t)l * C_ * C4_;
    size_t woq = (size_t)l * H_ * C_ * HS_;

    // weight repack: fp32 [K,N] -> bf16 [N,K]
    transpose_f2b<<<dim3(HS_/32, C_/32, H_), 256, 0, stream>>>(Wq + woq, WqT, HS_, C_, (size_t)C_*HS_, (size_t)HS_*C_);
    transpose_f2b<<<dim3(HS_/32, C_/32, H_), 256, 0, stream>>>(Wk + woq, WkT, HS_, C_, (size_t)C_*HS_, (size_t)HS_*C_);
    transpose_f2b<<<dim3(HS_/32, C_/32, H_), 256, 0, stream>>>(Wv + woq, WvT, HS_, C_, (size_t)C_*HS_, (size_t)HS_*C_);
    transpose_f2b<<<dim3(C_/32, C_/32, 1), 256, 0, stream>>>(Wp + wo, WpT, C_, C_, 0, 0);

    ln_kernel<<<M_, 256, 0, stream>>>(x, ln1g + (size_t)l*C_, ln1b + (size_t)l*C_, h);
    gemm_bt<64,64,3><<<dim3(C_/64, M_/64), 256, 0, stream>>>(h, WqT, nullptr, nullptr, qf, M_, C_, C_, C_);
    gemm_bt<64,64,3><<<dim3(C_/64, M_/64), 256, 0, stream>>>(h, WkT, nullptr, nullptr, kf, M_, C_, C_, C_);
    gemm_bt<64,64,3><<<dim3(C_/64, M_/64), 256, 0, stream>>>(h, WvT, nullptr, nullptr, vf, M_, C_, C_, C_);
    attn_naive<<<B_*H_*T_, 64, 0, stream>>>(qf, kf, vf, o);
    gemm_bt<64,64,2><<<dim3(C_/64, M_/64), 256, 0, stream>>>(o, WpT, bp + (size_t)l*C_, nullptr, x, M_, C_, C_, C_);

    ln_kernel<<<M_, 256, 0, stream>>>(x, ln2g + (size_t)l*C_, ln2b + (size_t)l*C_, h);
    transpose_f2b<<<dim3(C4_/32, C_/32, 1), 256, 0, stream>>>(W1 + wo4, W12T, C4_, C_, 0, 0);
    gemm_bt<128,128,1><<<dim3(C4_/128, M_/128), 256, 0, stream>>>(h, W12T, b1 + (size_t)l*C4_, mid, nullptr, M_, C4_, C_, C4_);
    transpose_f2b<<<dim3(C_/32, C4_/32, 1), 256, 0, stream>>>(W2 + wo4, W12T, C_, C4_, 0, 0);
    gemm_bt<64,64,2><<<dim3(C_/64, M_/64), 256, 0, stream>>>(mid, W12T, b2 + (size_t)l*C_, nullptr, x, M_, C_, C4_, C_);
  }

  // ---- final LN + chunked lm_head (fp32 store) ----
  ln_kernel<<<M_, 256, 0, stream>>>(x, lnfg, lnfb, h);
  for (int ci = 0; ci < V_/NVC_; ++ci) {
    transpose_f2b<<<dim3(NVC_/32, C_/32, 1), 256, 0, stream>>>(Wh + (size_t)ci*NVC_, WT, V_, C_, 0, 0);
    gemm_bt<128,128,3><<<dim3(NVC_/128, M_/128), 256, 0, stream>>>(
        h, WT, bh + (size_t)ci*NVC_, nullptr, out + (size_t)ci*NVC_, M_, NVC_, C_, V_);
  }
}

// Round 9
// 1864.514 us; speedup vs baseline: 7.4751x; 2.9505x over previous
//
#include <hip/hip_runtime.h>

// ---------------- problem constants ----------------
#define B_ 2
#define T_ 1024
#define C_ 768
#define H_ 12
#define L_ 6
#define V_ 32000
#define HS_ 64
#define M_ (B_*T_)            // 2048 token rows
#define C4_ (4*C_)            // 3072
#define NVC_ 6400             // lm_head column chunk (5 chunks)

typedef __attribute__((ext_vector_type(8))) short short8;
typedef __attribute__((ext_vector_type(4))) float f32x4;

__device__ __forceinline__ float b2f(unsigned short u) {
  union { unsigned int i; float f; } x; x.i = ((unsigned int)u) << 16; return x.f;
}
__device__ __forceinline__ unsigned short f2b(float f) {
  unsigned int u = __builtin_bit_cast(unsigned int, f);
  u += 0x7fffu + ((u >> 16) & 1u);
  return (unsigned short)(u >> 16);
}

// -------- transpose + fp32->bf16: out[c][r] = bf16(in[r][c]), z-batched (VALIDATED) --------
__global__ __launch_bounds__(256) void transpose_f2b(const float* __restrict__ in,
                                                     unsigned short* __restrict__ out,
                                                     int ldi, int ldo, size_t zi, size_t zo) {
  __shared__ unsigned short tile[32][33];
  in  += zi * blockIdx.z;
  out += zo * blockIdx.z;
  int c0 = blockIdx.x * 32, r0 = blockIdx.y * 32;
  int tx = threadIdx.x & 31, ty = threadIdx.x >> 5;   // 32 x 8
  #pragma unroll
  for (int j = 0; j < 32; j += 8)
    tile[ty + j][tx] = f2b(in[(size_t)(r0 + ty + j) * ldi + c0 + tx]);
  __syncthreads();
  #pragma unroll
  for (int j = 0; j < 32; j += 8)
    out[(size_t)(c0 + ty + j) * ldo + r0 + tx] = tile[tx][ty + j];
}

// ---------------- embedding: x = tok_emb[idx] + pos_emb (fp32) ----------------
__global__ __launch_bounds__(256) void embed_kernel(const int* __restrict__ idx,
                                                    const float* __restrict__ tok,
                                                    const float* __restrict__ pos,
                                                    float* __restrict__ x) {
  int m = blockIdx.x;
  int t = m & (T_ - 1);
  int tk = idx[m];
  #pragma unroll
  for (int i = 0; i < 3; ++i) {
    int c = threadIdx.x + i * 256;
    x[(size_t)m * C_ + c] = tok[(size_t)tk * C_ + c] + pos[(size_t)t * C_ + c];
  }
}

// ---------------- layernorm: h(bf16) = LN(x)*g + b   (x,g,b fp32) ----------------
__global__ __launch_bounds__(256) void ln_kernel(const float* __restrict__ x,
                                                 const float* __restrict__ g,
                                                 const float* __restrict__ bta,
                                                 unsigned short* __restrict__ h) {
  int m = blockIdx.x;
  const float* xr = x + (size_t)m * C_;
  float v[3], s = 0.f, ss = 0.f;
  #pragma unroll
  for (int i = 0; i < 3; ++i) {
    v[i] = xr[threadIdx.x + i * 256];
    s += v[i]; ss += v[i] * v[i];
  }
  #pragma unroll
  for (int off = 32; off; off >>= 1) { s += __shfl_xor(s, off); ss += __shfl_xor(ss, off); }
  __shared__ float red[8];
  int wave = threadIdx.x >> 6, lane = threadIdx.x & 63;
  if (lane == 0) { red[wave] = s; red[4 + wave] = ss; }
  __syncthreads();
  s  = red[0] + red[1] + red[2] + red[3];
  ss = red[4] + red[5] + red[6] + red[7];
  float mean = s * (1.f / C_);
  float var  = fmaxf(ss * (1.f / C_) - mean * mean, 0.f);
  float rstd = rsqrtf(var + 1e-5f);
  #pragma unroll
  for (int i = 0; i < 3; ++i) {
    int c = threadIdx.x + i * 256;
    h[(size_t)m * C_ + c] = f2b((v[i] - mean) * rstd * g[c] + bta[c]);
  }
}

// ---------------- MFMA flash attention ----------------
// Block: 64-query tile for one (b,h); 4 waves, each owns a 16-row strip.
// Fragment layouts identical to the validated gemm_bt (A-row/C-col = lane&15, etc.)
__global__ __launch_bounds__(256) void attn_mfma(const unsigned short* __restrict__ q,
                                                 const unsigned short* __restrict__ k,
                                                 const unsigned short* __restrict__ v,
                                                 unsigned short* __restrict__ o) {
  const float scale = 0.03608439182435161f;   // 768^-0.5 (reference scales by C, not HS)
  __shared__ __align__(16) unsigned short Qs[64 * 72];
  __shared__ __align__(16) unsigned short Ks[64 * 72];
  __shared__ __align__(16) unsigned short Vt[64 * 72];   // transposed: [d][kk]
  __shared__ __align__(16) unsigned short Ps[4][16 * 72]; // per-wave P, no cross-wave sharing

  int tid = threadIdx.x;
  int lane = tid & 63, wave = tid >> 6;
  int rl = lane & 15, kgrp = lane >> 4, koff = kgrp * 8;
  int qt = blockIdx.x;
  int bh = blockIdx.y;
  int hh = bh % H_, bb = bh / H_;
  size_t base = (size_t)bb * T_ * C_ + (size_t)hh * HS_;

  // stage Q tile (64 rows x 64 cols bf16)
  for (int e = tid; e < 512; e += 256) {
    int row = e >> 3, c8 = e & 7;
    *(short8*)&Qs[row * 72 + c8 * 8] =
        *(const short8*)&q[base + (size_t)(qt * 64 + row) * C_ + c8 * 8];
  }
  __syncthreads();
  short8 qf0 = *(const short8*)&Qs[(wave * 16 + rl) * 72 + koff];
  short8 qf1 = *(const short8*)&Qs[(wave * 16 + rl) * 72 + 32 + koff];

  float m_[4], l_[4];
  f32x4 oacc[4];
  #pragma unroll
  for (int r = 0; r < 4; ++r) { m_[r] = -INFINITY; l_[r] = 0.f; }
  #pragma unroll
  for (int j = 0; j < 4; ++j) oacc[j] = (f32x4){0.f, 0.f, 0.f, 0.f};

  for (int kt = 0; kt <= qt; ++kt) {
    // stage K tile + V^T tile
    for (int e = tid; e < 512; e += 256) {
      int row = e >> 3, c8 = e & 7;
      *(short8*)&Ks[row * 72 + c8 * 8] =
          *(const short8*)&k[base + (size_t)(kt * 64 + row) * C_ + c8 * 8];
    }
    for (int e = tid; e < 4096; e += 256) {
      int kk = e >> 6, d = e & 63;
      Vt[d * 72 + kk] = v[base + (size_t)(kt * 64 + kk) * C_ + d];
    }
    __syncthreads();

    // S = Q K^T  (per wave: 16 q-rows x 64 k-cols)
    f32x4 s[4];
    #pragma unroll
    for (int j = 0; j < 4; ++j) s[j] = (f32x4){0.f, 0.f, 0.f, 0.f};
    #pragma unroll
    for (int j = 0; j < 4; ++j) {
      short8 b0 = *(const short8*)&Ks[(j * 16 + rl) * 72 + koff];
      short8 b1 = *(const short8*)&Ks[(j * 16 + rl) * 72 + 32 + koff];
      s[j] = __builtin_amdgcn_mfma_f32_16x16x32_bf16(qf0, b0, s[j], 0, 0, 0);
      s[j] = __builtin_amdgcn_mfma_f32_16x16x32_bf16(qf1, b1, s[j], 0, 0, 0);
    }

    // scale + causal mask (diagonal tile only)
    bool diag = (kt == qt);
    #pragma unroll
    for (int j = 0; j < 4; ++j)
      #pragma unroll
      for (int r = 0; r < 4; ++r) {
        float sv = s[j][r] * scale;
        if (diag) {
          int urow = j * 16 + rl, qrow = wave * 16 + kgrp * 4 + r;
          if (urow > qrow) sv = -INFINITY;
        }
        s[j][r] = sv;
      }

    // online softmax (row = 16-lane group over rl)
    float rm[4], corr[4], rs[4];
    #pragma unroll
    for (int r = 0; r < 4; ++r) {
      float mrow = fmaxf(fmaxf(s[0][r], s[1][r]), fmaxf(s[2][r], s[3][r]));
      #pragma unroll
      for (int off = 8; off; off >>= 1) mrow = fmaxf(mrow, __shfl_xor(mrow, off));
      rm[r] = mrow;
      float mnew = fmaxf(m_[r], mrow);
      corr[r] = __expf(m_[r] - mnew);
      m_[r] = mnew;
    }
    #pragma unroll
    for (int r = 0; r < 4; ++r) rs[r] = 0.f;
    #pragma unroll
    for (int j = 0; j < 4; ++j)
      #pragma unroll
      for (int r = 0; r < 4; ++r) {
        float p = (s[j][r] == -INFINITY) ? 0.f : __expf(s[j][r] - m_[r]);
        s[j][r] = p;
        rs[r] += p;
      }
    #pragma unroll
    for (int r = 0; r < 4; ++r) {
      #pragma unroll
      for (int off = 8; off; off >>= 1) rs[r] += __shfl_xor(rs[r], off);
      l_[r] = l_[r] * corr[r] + rs[r];
    }
    #pragma unroll
    for (int j = 0; j < 4; ++j)
      #pragma unroll
      for (int r = 0; r < 4; ++r) oacc[j][r] *= corr[r];

    // P -> per-wave LDS (C-layout write, A-layout read)
    #pragma unroll
    for (int j = 0; j < 4; ++j)
      #pragma unroll
      for (int r = 0; r < 4; ++r)
        Ps[wave][(kgrp * 4 + r) * 72 + j * 16 + rl] = f2b(s[j][r]);

    // O += P V   (A = P[16 q][64 kk], B = Vt[d][kk])
    short8 pa0 = *(const short8*)&Ps[wave][rl * 72 + koff];
    short8 pa1 = *(const short8*)&Ps[wave][rl * 72 + 32 + koff];
    #pragma unroll
    for (int j = 0; j < 4; ++j) {
      short8 b0 = *(const short8*)&Vt[(j * 16 + rl) * 72 + koff];
      short8 b1 = *(const short8*)&Vt[(j * 16 + rl) * 72 + 32 + koff];
      oacc[j] = __builtin_amdgcn_mfma_f32_16x16x32_bf16(pa0, b0, oacc[j], 0, 0, 0);
      oacc[j] = __builtin_amdgcn_mfma_f32_16x16x32_bf16(pa1, b1, oacc[j], 0, 0, 0);
    }
    __syncthreads();   // protect Ks/Vt before next staging
  }

  // store O (bf16), divide by row sum
  #pragma unroll
  for (int j = 0; j < 4; ++j)
    #pragma unroll
    for (int r = 0; r < 4; ++r) {
      int qrow = wave * 16 + kgrp * 4 + r;
      o[base + (size_t)(qt * 64 + qrow) * C_ + j * 16 + rl] = f2b(oacc[j][r] / l_[r]);
    }
}

// ------- MFMA BT GEMM: out[M,N] = A[M,K](bf16) * Bt[N,K]^T(bf16) (+fp32 bias) — VALIDATED -------
// EPI: 0 = store bf16, 1 = relu bf16, 2 = fp32 residual +=, 3 = store fp32
template<int BM, int BN, int EPI>
__global__ __launch_bounds__(256) void gemm_bt(const unsigned short* __restrict__ A,
                                               const unsigned short* __restrict__ Bt,
                                               const float* __restrict__ bias,
                                               unsigned short* __restrict__ outb,
                                               float* __restrict__ outf,
                                               int M, int N, int K, int ldO) {
  constexpr int BK = 32;
  constexpr int LDT = BK + 8;
  __shared__ __align__(16) unsigned short As[BM * LDT];
  __shared__ __align__(16) unsigned short Bs[BN * LDT];
  constexpr int FM = BM / 32, FN = BN / 32;

  int tid = threadIdx.x;
  int lane = tid & 63, wave = tid >> 6;
  int wr = wave >> 1, wc = wave & 1;
  int m0 = blockIdx.y * BM, n0 = blockIdx.x * BN;
  int rl = lane & 15, koff = (lane >> 4) * 8;

  f32x4 acc[FM][FN] = {};

  for (int k0 = 0; k0 < K; k0 += BK) {
    #pragma unroll
    for (int e = tid; e < BM * 4; e += 256) {
      int row = e >> 2, c8 = e & 3;
      *(uint4*)&As[row * LDT + c8 * 8] =
          *(const uint4*)&A[(size_t)(m0 + row) * K + k0 + c8 * 8];
    }
    #pragma unroll
    for (int e = tid; e < BN * 4; e += 256) {
      int row = e >> 2, c8 = e & 3;
      *(uint4*)&Bs[row * LDT + c8 * 8] =
          *(const uint4*)&Bt[(size_t)(n0 + row) * K + k0 + c8 * 8];
    }
    __syncthreads();
    short8 af[FM], bfr[FN];
    #pragma unroll
    for (int i = 0; i < FM; ++i)
      af[i] = *(const short8*)&As[(wr * (BM / 2) + i * 16 + rl) * LDT + koff];
    #pragma unroll
    for (int j = 0; j < FN; ++j)
      bfr[j] = *(const short8*)&Bs[(wc * (BN / 2) + j * 16 + rl) * LDT + koff];
    #pragma unroll
    for (int i = 0; i < FM; ++i)
      #pragma unroll
      for (int j = 0; j < FN; ++j)
        acc[i][j] = __builtin_amdgcn_mfma_f32_16x16x32_bf16(af[i], bfr[j], acc[i][j], 0, 0, 0);
    __syncthreads();
  }

  int rbase = (lane >> 4) * 4;
  #pragma unroll
  for (int i = 0; i < FM; ++i) {
    #pragma unroll
    for (int j = 0; j < FN; ++j) {
      #pragma unroll
      for (int r = 0; r < 4; ++r) {
        int m = m0 + wr * (BM / 2) + i * 16 + rbase + r;
        int n = n0 + wc * (BN / 2) + j * 16 + (lane & 15);
        float val = acc[i][j][r];
        if (bias) val += bias[n];
        if (EPI == 0)      outb[(size_t)m * ldO + n] = f2b(val);
        else if (EPI == 1) outb[(size_t)m * ldO + n] = f2b(fmaxf(val, 0.f));
        else if (EPI == 2) outf[(size_t)m * ldO + n] += val;
        else               outf[(size_t)m * ldO + n] = val;
      }
    }
  }
}

// ---------------- host-side launch ----------------
extern "C" void kernel_launch(void* const* d_in, const int* in_sizes, int n_in,
                              void* d_out, int out_size, void* d_ws, size_t ws_size,
                              hipStream_t stream) {
  const int*   idx  = (const int*)d_in[0];
  const float* tok  = (const float*)d_in[1];
  const float* pos  = (const float*)d_in[2];
  const float* Wq   = (const float*)d_in[3];
  const float* Wk   = (const float*)d_in[4];
  const float* Wv   = (const float*)d_in[5];
  const float* Wp   = (const float*)d_in[6];
  const float* bp   = (const float*)d_in[7];
  const float* ln1g = (const float*)d_in[8];
  const float* ln1b = (const float*)d_in[9];
  const float* ln2g = (const float*)d_in[10];
  const float* ln2b = (const float*)d_in[11];
  const float* W1   = (const float*)d_in[12];
  const float* b1   = (const float*)d_in[13];
  const float* W2   = (const float*)d_in[14];
  const float* b2   = (const float*)d_in[15];
  const float* lnfg = (const float*)d_in[16];
  const float* lnfb = (const float*)d_in[17];
  const float* Wh   = (const float*)d_in[18];
  const float* bh   = (const float*)d_in[19];

  float* out = (float*)d_out;   // fp32 logits

  // ---- workspace: x(6.3) + h(3.15) + qkvo/mid(12.6) + WT(9.8) = 31.9 MB ----
  const size_t MC = (size_t)M_ * C_;
  const size_t need = MC*4 + MC*2 + MC*2*4 + (size_t)NVC_*C_*2;
  if (ws_size < need) return;

  char* p = (char*)d_ws;
  float*          x   = (float*)p;            p += MC*4;
  unsigned short* h   = (unsigned short*)p;   p += MC*2;
  unsigned short* qb  = (unsigned short*)p;   p += MC*2;
  unsigned short* kb  = (unsigned short*)p;   p += MC*2;
  unsigned short* vb  = (unsigned short*)p;   p += MC*2;
  unsigned short* ob  = (unsigned short*)p;   p += MC*2;
  unsigned short* WT  = (unsigned short*)p;   p += (size_t)NVC_*C_*2;
  unsigned short* mid = qb;                   // [M][C4] bf16 = 12.6MB, overlays qkvo (dead)

  unsigned short* WqT = WT;
  unsigned short* WkT = WT + (size_t)C_*C_;
  unsigned short* WvT = WT + (size_t)2*C_*C_;
  unsigned short* WpT = WT + (size_t)3*C_*C_;
  unsigned short* W12T = WT;

  embed_kernel<<<M_, 256, 0, stream>>>(idx, tok, pos, x);

  for (int l = 0; l < L_; ++l) {
    size_t wo  = (size_t)l * C_ * C_;
    size_t wo4 = (size_t)l * C_ * C4_;
    size_t woq = (size_t)l * H_ * C_ * HS_;

    transpose_f2b<<<dim3(HS_/32, C_/32, H_), 256, 0, stream>>>(Wq + woq, WqT, HS_, C_, (size_t)C_*HS_, (size_t)HS_*C_);
    transpose_f2b<<<dim3(HS_/32, C_/32, H_), 256, 0, stream>>>(Wk + woq, WkT, HS_, C_, (size_t)C_*HS_, (size_t)HS_*C_);
    transpose_f2b<<<dim3(HS_/32, C_/32, H_), 256, 0, stream>>>(Wv + woq, WvT, HS_, C_, (size_t)C_*HS_, (size_t)HS_*C_);
    transpose_f2b<<<dim3(C_/32, C_/32, 1), 256, 0, stream>>>(Wp + wo, WpT, C_, C_, 0, 0);

    ln_kernel<<<M_, 256, 0, stream>>>(x, ln1g + (size_t)l*C_, ln1b + (size_t)l*C_, h);
    gemm_bt<64,64,0><<<dim3(C_/64, M_/64), 256, 0, stream>>>(h, WqT, nullptr, qb, nullptr, M_, C_, C_, C_);
    gemm_bt<64,64,0><<<dim3(C_/64, M_/64), 256, 0, stream>>>(h, WkT, nullptr, kb, nullptr, M_, C_, C_, C_);
    gemm_bt<64,64,0><<<dim3(C_/64, M_/64), 256, 0, stream>>>(h, WvT, nullptr, vb, nullptr, M_, C_, C_, C_);
    attn_mfma<<<dim3(T_/64, B_*H_), 256, 0, stream>>>(qb, kb, vb, ob);
    gemm_bt<64,64,2><<<dim3(C_/64, M_/64), 256, 0, stream>>>(ob, WpT, bp + (size_t)l*C_, nullptr, x, M_, C_, C_, C_);

    ln_kernel<<<M_, 256, 0, stream>>>(x, ln2g + (size_t)l*C_, ln2b + (size_t)l*C_, h);
    transpose_f2b<<<dim3(C4_/32, C_/32, 1), 256, 0, stream>>>(W1 + wo4, W12T, C4_, C_, 0, 0);
    gemm_bt<128,128,1><<<dim3(C4_/128, M_/128), 256, 0, stream>>>(h, W12T, b1 + (size_t)l*C4_, mid, nullptr, M_, C4_, C_, C4_);
    transpose_f2b<<<dim3(C_/32, C4_/32, 1), 256, 0, stream>>>(W2 + wo4, W12T, C_, C4_, 0, 0);
    gemm_bt<64,64,2><<<dim3(C_/64, M_/64), 256, 0, stream>>>(mid, W12T, b2 + (size_t)l*C_, nullptr, x, M_, C_, C4_, C_);
  }

  // ---- final LN + chunked lm_head (fp32 store) ----
  ln_kernel<<<M_, 256, 0, stream>>>(x, lnfg, lnfb, h);
  for (int ci = 0; ci < V_/NVC_; ++ci) {
    transpose_f2b<<<dim3(NVC_/32, C_/32, 1), 256, 0, stream>>>(Wh + (size_t)ci*NVC_, WT, V_, C_, 0, 0);
    gemm_bt<128,128,3><<<dim3(NVC_/128, M_/128), 256, 0, stream>>>(
        h, WT, bh + (size_t)ci*NVC_, nullptr, out + (size_t)ci*NVC_, M_, NVC_, C_, V_);
  }
}

// Round 10
// 1606.973 us; speedup vs baseline: 8.6731x; 1.1603x over previous
//
#include <hip/hip_runtime.h>

// ---------------- problem constants ----------------
#define B_ 2
#define T_ 1024
#define C_ 768
#define H_ 12
#define L_ 6
#define V_ 32000
#define HS_ 64
#define M_ (B_*T_)            // 2048 token rows
#define C4_ (4*C_)            // 3072
#define NVC_ 6400             // lm_head column chunk (5 chunks)

typedef __attribute__((ext_vector_type(8))) short short8;
typedef __attribute__((ext_vector_type(4))) float f32x4;

__device__ __forceinline__ float b2f(unsigned short u) {
  union { unsigned int i; float f; } x; x.i = ((unsigned int)u) << 16; return x.f;
}
__device__ __forceinline__ unsigned short f2b(float f) {
  unsigned int u = __builtin_bit_cast(unsigned int, f);
  u += 0x7fffu + ((u >> 16) & 1u);
  return (unsigned short)(u >> 16);
}

// async global->LDS, 16B per lane; LDS dest wave-uniform, lanes write dest + lane*16
__device__ __forceinline__ void gload16(const unsigned short* g, unsigned short* l) {
  __builtin_amdgcn_global_load_lds(
      (const __attribute__((address_space(1))) unsigned int*)g,
      (__attribute__((address_space(3))) unsigned int*)l, 16, 0, 0);
}

// -------- transpose + fp32->bf16: out[c][r] = bf16(in[r][c]), z-batched (VALIDATED) --------
__global__ __launch_bounds__(256) void transpose_f2b(const float* __restrict__ in,
                                                     unsigned short* __restrict__ out,
                                                     int ldi, int ldo, size_t zi, size_t zo) {
  __shared__ unsigned short tile[32][33];
  in  += zi * blockIdx.z;
  out += zo * blockIdx.z;
  int c0 = blockIdx.x * 32, r0 = blockIdx.y * 32;
  int tx = threadIdx.x & 31, ty = threadIdx.x >> 5;   // 32 x 8
  #pragma unroll
  for (int j = 0; j < 32; j += 8)
    tile[ty + j][tx] = f2b(in[(size_t)(r0 + ty + j) * ldi + c0 + tx]);
  __syncthreads();
  #pragma unroll
  for (int j = 0; j < 32; j += 8)
    out[(size_t)(c0 + ty + j) * ldo + r0 + tx] = tile[tx][ty + j];
}

// ---------------- embedding: x = tok_emb[idx] + pos_emb (fp32) ----------------
__global__ __launch_bounds__(256) void embed_kernel(const int* __restrict__ idx,
                                                    const float* __restrict__ tok,
                                                    const float* __restrict__ pos,
                                                    float* __restrict__ x) {
  int m = blockIdx.x;
  int t = m & (T_ - 1);
  int tk = idx[m];
  #pragma unroll
  for (int i = 0; i < 3; ++i) {
    int c = threadIdx.x + i * 256;
    x[(size_t)m * C_ + c] = tok[(size_t)tk * C_ + c] + pos[(size_t)t * C_ + c];
  }
}

// ---------------- layernorm: h(bf16) = LN(x)*g + b   (x,g,b fp32) ----------------
__global__ __launch_bounds__(256) void ln_kernel(const float* __restrict__ x,
                                                 const float* __restrict__ g,
                                                 const float* __restrict__ bta,
                                                 unsigned short* __restrict__ h) {
  int m = blockIdx.x;
  const float* xr = x + (size_t)m * C_;
  float v[3], s = 0.f, ss = 0.f;
  #pragma unroll
  for (int i = 0; i < 3; ++i) {
    v[i] = xr[threadIdx.x + i * 256];
    s += v[i]; ss += v[i] * v[i];
  }
  #pragma unroll
  for (int off = 32; off; off >>= 1) { s += __shfl_xor(s, off); ss += __shfl_xor(ss, off); }
  __shared__ float red[8];
  int wave = threadIdx.x >> 6, lane = threadIdx.x & 63;
  if (lane == 0) { red[wave] = s; red[4 + wave] = ss; }
  __syncthreads();
  s  = red[0] + red[1] + red[2] + red[3];
  ss = red[4] + red[5] + red[6] + red[7];
  float mean = s * (1.f / C_);
  float var  = fmaxf(ss * (1.f / C_) - mean * mean, 0.f);
  float rstd = rsqrtf(var + 1e-5f);
  #pragma unroll
  for (int i = 0; i < 3; ++i) {
    int c = threadIdx.x + i * 256;
    h[(size_t)m * C_ + c] = f2b((v[i] - mean) * rstd * g[c] + bta[c]);
  }
}

// ---------------- MFMA flash attention (VALIDATED r9) ----------------
__global__ __launch_bounds__(256) void attn_mfma(const unsigned short* __restrict__ q,
                                                 const unsigned short* __restrict__ k,
                                                 const unsigned short* __restrict__ v,
                                                 unsigned short* __restrict__ o) {
  const float scale = 0.03608439182435161f;   // 768^-0.5 (reference scales by C, not HS)
  __shared__ __align__(16) unsigned short Qs[64 * 72];
  __shared__ __align__(16) unsigned short Ks[64 * 72];
  __shared__ __align__(16) unsigned short Vt[64 * 72];   // transposed: [d][kk]
  __shared__ __align__(16) unsigned short Ps[4][16 * 72]; // per-wave P

  int tid = threadIdx.x;
  int lane = tid & 63, wave = tid >> 6;
  int rl = lane & 15, kgrp = lane >> 4, koff = kgrp * 8;
  int qt = blockIdx.x;
  int bh = blockIdx.y;
  int hh = bh % H_, bb = bh / H_;
  size_t base = (size_t)bb * T_ * C_ + (size_t)hh * HS_;

  for (int e = tid; e < 512; e += 256) {
    int row = e >> 3, c8 = e & 7;
    *(short8*)&Qs[row * 72 + c8 * 8] =
        *(const short8*)&q[base + (size_t)(qt * 64 + row) * C_ + c8 * 8];
  }
  __syncthreads();
  short8 qf0 = *(const short8*)&Qs[(wave * 16 + rl) * 72 + koff];
  short8 qf1 = *(const short8*)&Qs[(wave * 16 + rl) * 72 + 32 + koff];

  float m_[4], l_[4];
  f32x4 oacc[4];
  #pragma unroll
  for (int r = 0; r < 4; ++r) { m_[r] = -INFINITY; l_[r] = 0.f; }
  #pragma unroll
  for (int j = 0; j < 4; ++j) oacc[j] = (f32x4){0.f, 0.f, 0.f, 0.f};

  for (int kt = 0; kt <= qt; ++kt) {
    for (int e = tid; e < 512; e += 256) {
      int row = e >> 3, c8 = e & 7;
      *(short8*)&Ks[row * 72 + c8 * 8] =
          *(const short8*)&k[base + (size_t)(kt * 64 + row) * C_ + c8 * 8];
    }
    for (int e = tid; e < 4096; e += 256) {
      int kk = e >> 6, d = e & 63;
      Vt[d * 72 + kk] = v[base + (size_t)(kt * 64 + kk) * C_ + d];
    }
    __syncthreads();

    f32x4 s[4];
    #pragma unroll
    for (int j = 0; j < 4; ++j) s[j] = (f32x4){0.f, 0.f, 0.f, 0.f};
    #pragma unroll
    for (int j = 0; j < 4; ++j) {
      short8 b0 = *(const short8*)&Ks[(j * 16 + rl) * 72 + koff];
      short8 b1 = *(const short8*)&Ks[(j * 16 + rl) * 72 + 32 + koff];
      s[j] = __builtin_amdgcn_mfma_f32_16x16x32_bf16(qf0, b0, s[j], 0, 0, 0);
      s[j] = __builtin_amdgcn_mfma_f32_16x16x32_bf16(qf1, b1, s[j], 0, 0, 0);
    }

    bool diag = (kt == qt);
    #pragma unroll
    for (int j = 0; j < 4; ++j)
      #pragma unroll
      for (int r = 0; r < 4; ++r) {
        float sv = s[j][r] * scale;
        if (diag) {
          int urow = j * 16 + rl, qrow = wave * 16 + kgrp * 4 + r;
          if (urow > qrow) sv = -INFINITY;
        }
        s[j][r] = sv;
      }

    float corr[4], rs[4];
    #pragma unroll
    for (int r = 0; r < 4; ++r) {
      float mrow = fmaxf(fmaxf(s[0][r], s[1][r]), fmaxf(s[2][r], s[3][r]));
      #pragma unroll
      for (int off = 8; off; off >>= 1) mrow = fmaxf(mrow, __shfl_xor(mrow, off));
      float mnew = fmaxf(m_[r], mrow);
      corr[r] = __expf(m_[r] - mnew);
      m_[r] = mnew;
    }
    #pragma unroll
    for (int r = 0; r < 4; ++r) rs[r] = 0.f;
    #pragma unroll
    for (int j = 0; j < 4; ++j)
      #pragma unroll
      for (int r = 0; r < 4; ++r) {
        float p = (s[j][r] == -INFINITY) ? 0.f : __expf(s[j][r] - m_[r]);
        s[j][r] = p;
        rs[r] += p;
      }
    #pragma unroll
    for (int r = 0; r < 4; ++r) {
      #pragma unroll
      for (int off = 8; off; off >>= 1) rs[r] += __shfl_xor(rs[r], off);
      l_[r] = l_[r] * corr[r] + rs[r];
    }
    #pragma unroll
    for (int j = 0; j < 4; ++j)
      #pragma unroll
      for (int r = 0; r < 4; ++r) oacc[j][r] *= corr[r];

    #pragma unroll
    for (int j = 0; j < 4; ++j)
      #pragma unroll
      for (int r = 0; r < 4; ++r)
        Ps[wave][(kgrp * 4 + r) * 72 + j * 16 + rl] = f2b(s[j][r]);

    short8 pa0 = *(const short8*)&Ps[wave][rl * 72 + koff];
    short8 pa1 = *(const short8*)&Ps[wave][rl * 72 + 32 + koff];
    #pragma unroll
    for (int j = 0; j < 4; ++j) {
      short8 b0 = *(const short8*)&Vt[(j * 16 + rl) * 72 + koff];
      short8 b1 = *(const short8*)&Vt[(j * 16 + rl) * 72 + 32 + koff];
      oacc[j] = __builtin_amdgcn_mfma_f32_16x16x32_bf16(pa0, b0, oacc[j], 0, 0, 0);
      oacc[j] = __builtin_amdgcn_mfma_f32_16x16x32_bf16(pa1, b1, oacc[j], 0, 0, 0);
    }
    __syncthreads();
  }

  #pragma unroll
  for (int j = 0; j < 4; ++j)
    #pragma unroll
    for (int r = 0; r < 4; ++r) {
      int qrow = wave * 16 + kgrp * 4 + r;
      o[base + (size_t)(qt * 64 + qrow) * C_ + j * 16 + rl] = f2b(oacc[j][r] / l_[r]);
    }
}

// ------- MFMA BT GEMM, m97-style staging: global_load_lds width-16, linear LDS -------
// out[M, N] = A[M,K](bf16) * Bt[N,K]^T(bf16) (+fp32 bias); z-batch via zBt/zOut.
// EPI: 0 = store bf16, 1 = relu bf16, 2 = fp32 residual +=, 3 = store fp32
template<int BM, int BN, int EPI>
__global__ __launch_bounds__(256) void gemm_bt(const unsigned short* __restrict__ A,
                                               const unsigned short* __restrict__ Bt,
                                               const float* __restrict__ bias,
                                               unsigned short* __restrict__ outb,
                                               float* __restrict__ outf,
                                               int M, int N, int K, int ldO,
                                               size_t zBt, size_t zOut) {
  constexpr int BK = 32;
  __shared__ __align__(16) unsigned short As[BM * BK];
  __shared__ __align__(16) unsigned short Bs[BN * BK];
  constexpr int FM = BM / 32, FN = BN / 32;

  int tid = threadIdx.x;
  int lane = tid & 63, wave = tid >> 6;
  int wr = wave >> 1, wc = wave & 1;
  int m0 = blockIdx.y * BM, n0 = blockIdx.x * BN;
  int rl = lane & 15, koff = (lane >> 4) * 8;
  Bt += zBt * blockIdx.z;

  // staging: one gload16 covers 16 rows (64B each); lane l -> row l>>2, 8-elem seg l&3
  int srow = lane >> 2, sseg = (lane & 3) * 8;

  f32x4 acc[FM][FN] = {};

  for (int k0 = 0; k0 < K; k0 += BK) {
    #pragma unroll
    for (int i = 0; i < BM / 64; ++i) {
      int r = i * 64 + wave * 16;            // wave-uniform LDS row base
      gload16(&A[(size_t)(m0 + r + srow) * K + k0 + sseg], &As[r * BK]);
    }
    #pragma unroll
    for (int i = 0; i < BN / 64; ++i) {
      int r = i * 64 + wave * 16;
      gload16(&Bt[(size_t)(n0 + r + srow) * K + k0 + sseg], &Bs[r * BK]);
    }
    __syncthreads();   // compiler emits s_waitcnt vmcnt(0) before s_barrier

    short8 af[FM], bfr[FN];
    #pragma unroll
    for (int i = 0; i < FM; ++i)
      af[i] = *(const short8*)&As[(wr * (BM / 2) + i * 16 + rl) * BK + koff];
    #pragma unroll
    for (int j = 0; j < FN; ++j)
      bfr[j] = *(const short8*)&Bs[(wc * (BN / 2) + j * 16 + rl) * BK + koff];
    #pragma unroll
    for (int i = 0; i < FM; ++i)
      #pragma unroll
      for (int j = 0; j < FN; ++j)
        acc[i][j] = __builtin_amdgcn_mfma_f32_16x16x32_bf16(af[i], bfr[j], acc[i][j], 0, 0, 0);
    __syncthreads();
  }

  int rbase = (lane >> 4) * 4;
  #pragma unroll
  for (int i = 0; i < FM; ++i) {
    #pragma unroll
    for (int j = 0; j < FN; ++j) {
      #pragma unroll
      for (int r = 0; r < 4; ++r) {
        int m = m0 + wr * (BM / 2) + i * 16 + rbase + r;
        int n = n0 + wc * (BN / 2) + j * 16 + (lane & 15);
        float val = acc[i][j][r];
        if (bias) val += bias[n];
        if (EPI == 0)      (outb + zOut * blockIdx.z)[(size_t)m * ldO + n] = f2b(val);
        else if (EPI == 1) (outb + zOut * blockIdx.z)[(size_t)m * ldO + n] = f2b(fmaxf(val, 0.f));
        else if (EPI == 2) (outf + zOut * blockIdx.z)[(size_t)m * ldO + n] += val;
        else               (outf + zOut * blockIdx.z)[(size_t)m * ldO + n] = val;
      }
    }
  }
}

// ---------------- host-side launch ----------------
extern "C" void kernel_launch(void* const* d_in, const int* in_sizes, int n_in,
                              void* d_out, int out_size, void* d_ws, size_t ws_size,
                              hipStream_t stream) {
  const int*   idx  = (const int*)d_in[0];
  const float* tok  = (const float*)d_in[1];
  const float* pos  = (const float*)d_in[2];
  const float* Wq   = (const float*)d_in[3];
  const float* Wk   = (const float*)d_in[4];
  const float* Wv   = (const float*)d_in[5];
  const float* Wp   = (const float*)d_in[6];
  const float* bp   = (const float*)d_in[7];
  const float* ln1g = (const float*)d_in[8];
  const float* ln1b = (const float*)d_in[9];
  const float* ln2g = (const float*)d_in[10];
  const float* ln2b = (const float*)d_in[11];
  const float* W1   = (const float*)d_in[12];
  const float* b1   = (const float*)d_in[13];
  const float* W2   = (const float*)d_in[14];
  const float* b2   = (const float*)d_in[15];
  const float* lnfg = (const float*)d_in[16];
  const float* lnfb = (const float*)d_in[17];
  const float* Wh   = (const float*)d_in[18];
  const float* bh   = (const float*)d_in[19];

  float* out = (float*)d_out;   // fp32 logits

  // ---- workspace: x(6.3) + h(3.15) + qkvo/mid(12.6) + WT(9.8) = 31.9 MB ----
  const size_t MC = (size_t)M_ * C_;
  const size_t need = MC*4 + MC*2 + MC*2*4 + (size_t)NVC_*C_*2;
  if (ws_size < need) return;

  char* p = (char*)d_ws;
  float*          x   = (float*)p;            p += MC*4;
  unsigned short* h   = (unsigned short*)p;   p += MC*2;
  unsigned short* qb  = (unsigned short*)p;   p += MC*2;   // qb,kb,vb contiguous (z-batch)
  unsigned short* kb  = (unsigned short*)p;   p += MC*2;
  unsigned short* vb  = (unsigned short*)p;   p += MC*2;
  unsigned short* ob  = (unsigned short*)p;   p += MC*2;
  unsigned short* WT  = (unsigned short*)p;   p += (size_t)NVC_*C_*2;
  unsigned short* mid = qb;                   // [M][C4] bf16, overlays qkvo (dead)

  unsigned short* WqT = WT;                   // WqT,WkT,WvT contiguous (z-batch)
  unsigned short* WpT = WT + (size_t)3*C_*C_;
  unsigned short* W12T = WT;

  embed_kernel<<<M_, 256, 0, stream>>>(idx, tok, pos, x);

  for (int l = 0; l < L_; ++l) {
    size_t wo  = (size_t)l * C_ * C_;
    size_t wo4 = (size_t)l * C_ * C4_;
    size_t woq = (size_t)l * H_ * C_ * HS_;

    transpose_f2b<<<dim3(HS_/32, C_/32, H_), 256, 0, stream>>>(Wq + woq, WqT, HS_, C_, (size_t)C_*HS_, (size_t)HS_*C_);
    transpose_f2b<<<dim3(HS_/32, C_/32, H_), 256, 0, stream>>>(Wk + woq, WqT + (size_t)C_*C_, HS_, C_, (size_t)C_*HS_, (size_t)HS_*C_);
    transpose_f2b<<<dim3(HS_/32, C_/32, H_), 256, 0, stream>>>(Wv + woq, WqT + (size_t)2*C_*C_, HS_, C_, (size_t)C_*HS_, (size_t)HS_*C_);
    transpose_f2b<<<dim3(C_/32, C_/32, 1), 256, 0, stream>>>(Wp + wo, WpT, C_, C_, 0, 0);

    ln_kernel<<<M_, 256, 0, stream>>>(x, ln1g + (size_t)l*C_, ln1b + (size_t)l*C_, h);
    // fused QKV: z in {0,1,2} -> Bt = WqT + z*C*C, out = qb + z*MC
    gemm_bt<64,64,0><<<dim3(C_/64, M_/64, 3), 256, 0, stream>>>(h, WqT, nullptr, qb, nullptr,
                                                                M_, C_, C_, C_, (size_t)C_*C_, MC);
    attn_mfma<<<dim3(T_/64, B_*H_), 256, 0, stream>>>(qb, kb, vb, ob);
    gemm_bt<64,64,2><<<dim3(C_/64, M_/64), 256, 0, stream>>>(ob, WpT, bp + (size_t)l*C_, nullptr, x,
                                                             M_, C_, C_, C_, 0, 0);

    ln_kernel<<<M_, 256, 0, stream>>>(x, ln2g + (size_t)l*C_, ln2b + (size_t)l*C_, h);
    transpose_f2b<<<dim3(C4_/32, C_/32, 1), 256, 0, stream>>>(W1 + wo4, W12T, C4_, C_, 0, 0);
    gemm_bt<128,128,1><<<dim3(C4_/128, M_/128), 256, 0, stream>>>(h, W12T, b1 + (size_t)l*C4_, mid, nullptr,
                                                                  M_, C4_, C_, C4_, 0, 0);
    transpose_f2b<<<dim3(C_/32, C4_/32, 1), 256, 0, stream>>>(W2 + wo4, W12T, C_, C4_, 0, 0);
    gemm_bt<64,64,2><<<dim3(C_/64, M_/64), 256, 0, stream>>>(mid, W12T, b2 + (size_t)l*C_, nullptr, x,
                                                             M_, C_, C4_, C_, 0, 0);
  }

  // ---- final LN + chunked lm_head (fp32 store) ----
  ln_kernel<<<M_, 256, 0, stream>>>(x, lnfg, lnfb, h);
  for (int ci = 0; ci < V_/NVC_; ++ci) {
    transpose_f2b<<<dim3(NVC_/32, C_/32, 1), 256, 0, stream>>>(Wh + (size_t)ci*NVC_, WT, V_, C_, 0, 0);
    gemm_bt<128,128,3><<<dim3(NVC_/128, M_/128), 256, 0, stream>>>(
        h, WT, bh + (size_t)ci*NVC_, nullptr, out + (size_t)ci*NVC_, M_, NVC_, C_, V_, 0, 0);
  }
}

// Round 11
// 1579.333 us; speedup vs baseline: 8.8249x; 1.0175x over previous
//
#include <hip/hip_runtime.h>

// ---------------- problem constants ----------------
#define B_ 2
#define T_ 1024
#define C_ 768
#define H_ 12
#define L_ 6
#define V_ 32000
#define HS_ 64
#define M_ (B_*T_)            // 2048 token rows
#define C4_ (4*C_)            // 3072
#define NVC_ 6400             // lm_head column chunk (5 chunks)

typedef __attribute__((ext_vector_type(8))) short short8;
typedef __attribute__((ext_vector_type(4))) float f32x4;

__device__ __forceinline__ float b2f(unsigned short u) {
  union { unsigned int i; float f; } x; x.i = ((unsigned int)u) << 16; return x.f;
}
__device__ __forceinline__ unsigned short f2b(float f) {
  unsigned int u = __builtin_bit_cast(unsigned int, f);
  u += 0x7fffu + ((u >> 16) & 1u);
  return (unsigned short)(u >> 16);
}

// async global->LDS, 16B per lane; LDS dest wave-uniform, lanes write dest + lane*16
__device__ __forceinline__ void gload16(const unsigned short* g, unsigned short* l) {
  __builtin_amdgcn_global_load_lds(
      (const __attribute__((address_space(1))) unsigned int*)g,
      (__attribute__((address_space(3))) unsigned int*)l, 16, 0, 0);
}

// -------- transpose + fp32->bf16: out[c][r] = bf16(in[r][c]), z-batched (VALIDATED) --------
__global__ __launch_bounds__(256) void transpose_f2b(const float* __restrict__ in,
                                                     unsigned short* __restrict__ out,
                                                     int ldi, int ldo, size_t zi, size_t zo) {
  __shared__ unsigned short tile[32][33];
  in  += zi * blockIdx.z;
  out += zo * blockIdx.z;
  int c0 = blockIdx.x * 32, r0 = blockIdx.y * 32;
  int tx = threadIdx.x & 31, ty = threadIdx.x >> 5;   // 32 x 8
  #pragma unroll
  for (int j = 0; j < 32; j += 8)
    tile[ty + j][tx] = f2b(in[(size_t)(r0 + ty + j) * ldi + c0 + tx]);
  __syncthreads();
  #pragma unroll
  for (int j = 0; j < 32; j += 8)
    out[(size_t)(c0 + ty + j) * ldo + r0 + tx] = tile[tx][ty + j];
}

// -------- merged QKV head-transpose: z in [0,36) -> {Wq,Wk,Wv}[head] [C][HS] -> [HS][C] --------
__global__ __launch_bounds__(256) void transpose_qkv(const float* __restrict__ Wq,
                                                     const float* __restrict__ Wk,
                                                     const float* __restrict__ Wv,
                                                     unsigned short* __restrict__ out) {
  __shared__ unsigned short tile[32][33];
  int z = blockIdx.z;
  int which = z / H_, hh = z % H_;
  const float* in = (which == 0 ? Wq : which == 1 ? Wk : Wv) + (size_t)hh * C_ * HS_;
  unsigned short* o = out + (size_t)which * C_ * C_ + (size_t)hh * HS_ * C_;
  int c0 = blockIdx.x * 32, r0 = blockIdx.y * 32;   // c over HS (grid.x=2), r over C (grid.y=24)
  int tx = threadIdx.x & 31, ty = threadIdx.x >> 5;
  #pragma unroll
  for (int j = 0; j < 32; j += 8)
    tile[ty + j][tx] = f2b(in[(size_t)(r0 + ty + j) * HS_ + c0 + tx]);
  __syncthreads();
  #pragma unroll
  for (int j = 0; j < 32; j += 8)
    o[(size_t)(c0 + ty + j) * C_ + r0 + tx] = tile[tx][ty + j];
}

// ---------------- embedding: x = tok_emb[idx] + pos_emb (fp32) ----------------
__global__ __launch_bounds__(256) void embed_kernel(const int* __restrict__ idx,
                                                    const float* __restrict__ tok,
                                                    const float* __restrict__ pos,
                                                    float* __restrict__ x) {
  int m = blockIdx.x;
  int t = m & (T_ - 1);
  int tk = idx[m];
  #pragma unroll
  for (int i = 0; i < 3; ++i) {
    int c = threadIdx.x + i * 256;
    x[(size_t)m * C_ + c] = tok[(size_t)tk * C_ + c] + pos[(size_t)t * C_ + c];
  }
}

// ---------------- layernorm: h(bf16) = LN(x)*g + b   (x,g,b fp32) ----------------
__global__ __launch_bounds__(256) void ln_kernel(const float* __restrict__ x,
                                                 const float* __restrict__ g,
                                                 const float* __restrict__ bta,
                                                 unsigned short* __restrict__ h) {
  int m = blockIdx.x;
  const float* xr = x + (size_t)m * C_;
  float v[3], s = 0.f, ss = 0.f;
  #pragma unroll
  for (int i = 0; i < 3; ++i) {
    v[i] = xr[threadIdx.x + i * 256];
    s += v[i]; ss += v[i] * v[i];
  }
  #pragma unroll
  for (int off = 32; off; off >>= 1) { s += __shfl_xor(s, off); ss += __shfl_xor(ss, off); }
  __shared__ float red[8];
  int wave = threadIdx.x >> 6, lane = threadIdx.x & 63;
  if (lane == 0) { red[wave] = s; red[4 + wave] = ss; }
  __syncthreads();
  s  = red[0] + red[1] + red[2] + red[3];
  ss = red[4] + red[5] + red[6] + red[7];
  float mean = s * (1.f / C_);
  float var  = fmaxf(ss * (1.f / C_) - mean * mean, 0.f);
  float rstd = rsqrtf(var + 1e-5f);
  #pragma unroll
  for (int i = 0; i < 3; ++i) {
    int c = threadIdx.x + i * 256;
    h[(size_t)m * C_ + c] = f2b((v[i] - mean) * rstd * g[c] + bta[c]);
  }
}

// ---------------- MFMA flash attention (r9-validated math; V staging vectorized) ----------------
__global__ __launch_bounds__(256) void attn_mfma(const unsigned short* __restrict__ q,
                                                 const unsigned short* __restrict__ k,
                                                 const unsigned short* __restrict__ v,
                                                 unsigned short* __restrict__ o) {
  const float scale = 0.03608439182435161f;   // 768^-0.5 (reference scales by C, not HS)
  __shared__ __align__(16) unsigned short Qs[64 * 72];
  __shared__ __align__(16) unsigned short Ks[64 * 72];
  __shared__ __align__(16) unsigned short Vt[64 * 72];   // transposed: [d][kk]
  __shared__ __align__(16) unsigned short Ps[4][16 * 72]; // per-wave P

  int tid = threadIdx.x;
  int lane = tid & 63, wave = tid >> 6;
  int rl = lane & 15, kgrp = lane >> 4, koff = kgrp * 8;
  int qt = blockIdx.x;
  int bh = blockIdx.y;
  int hh = bh % H_, bb = bh / H_;
  size_t base = (size_t)bb * T_ * C_ + (size_t)hh * HS_;

  for (int e = tid; e < 512; e += 256) {
    int row = e >> 3, c8 = e & 7;
    *(short8*)&Qs[row * 72 + c8 * 8] =
        *(const short8*)&q[base + (size_t)(qt * 64 + row) * C_ + c8 * 8];
  }
  __syncthreads();
  short8 qf0 = *(const short8*)&Qs[(wave * 16 + rl) * 72 + koff];
  short8 qf1 = *(const short8*)&Qs[(wave * 16 + rl) * 72 + 32 + koff];

  float m_[4], l_[4];
  f32x4 oacc[4];
  #pragma unroll
  for (int r = 0; r < 4; ++r) { m_[r] = -INFINITY; l_[r] = 0.f; }
  #pragma unroll
  for (int j = 0; j < 4; ++j) oacc[j] = (f32x4){0.f, 0.f, 0.f, 0.f};

  for (int kt = 0; kt <= qt; ++kt) {
    // K tile: vec8 rows
    for (int e = tid; e < 512; e += 256) {
      int row = e >> 3, c8 = e & 7;
      *(short8*)&Ks[row * 72 + c8 * 8] =
          *(const short8*)&k[base + (size_t)(kt * 64 + row) * C_ + c8 * 8];
    }
    // V^T tile: vec8 global loads (8 d for one kk), rotated scatter to avoid bank pile-up
    for (int e = tid; e < 512; e += 256) {
      int kk = e >> 3, d8 = (e & 7) * 8;
      short8 vv = *(const short8*)&v[base + (size_t)(kt * 64 + kk) * C_ + d8];
      #pragma unroll
      for (int i = 0; i < 8; ++i) {
        int ii = (i + tid) & 7;
        Vt[(d8 + ii) * 72 + kk] = vv[ii];
      }
    }
    __syncthreads();

    f32x4 s[4];
    #pragma unroll
    for (int j = 0; j < 4; ++j) s[j] = (f32x4){0.f, 0.f, 0.f, 0.f};
    #pragma unroll
    for (int j = 0; j < 4; ++j) {
      short8 b0 = *(const short8*)&Ks[(j * 16 + rl) * 72 + koff];
      short8 b1 = *(const short8*)&Ks[(j * 16 + rl) * 72 + 32 + koff];
      s[j] = __builtin_amdgcn_mfma_f32_16x16x32_bf16(qf0, b0, s[j], 0, 0, 0);
      s[j] = __builtin_amdgcn_mfma_f32_16x16x32_bf16(qf1, b1, s[j], 0, 0, 0);
    }

    bool diag = (kt == qt);
    #pragma unroll
    for (int j = 0; j < 4; ++j)
      #pragma unroll
      for (int r = 0; r < 4; ++r) {
        float sv = s[j][r] * scale;
        if (diag) {
          int urow = j * 16 + rl, qrow = wave * 16 + kgrp * 4 + r;
          if (urow > qrow) sv = -INFINITY;
        }
        s[j][r] = sv;
      }

    float corr[4], rs[4];
    #pragma unroll
    for (int r = 0; r < 4; ++r) {
      float mrow = fmaxf(fmaxf(s[0][r], s[1][r]), fmaxf(s[2][r], s[3][r]));
      #pragma unroll
      for (int off = 8; off; off >>= 1) mrow = fmaxf(mrow, __shfl_xor(mrow, off));
      float mnew = fmaxf(m_[r], mrow);
      corr[r] = __expf(m_[r] - mnew);
      m_[r] = mnew;
    }
    #pragma unroll
    for (int r = 0; r < 4; ++r) rs[r] = 0.f;
    #pragma unroll
    for (int j = 0; j < 4; ++j)
      #pragma unroll
      for (int r = 0; r < 4; ++r) {
        float p = (s[j][r] == -INFINITY) ? 0.f : __expf(s[j][r] - m_[r]);
        s[j][r] = p;
        rs[r] += p;
      }
    #pragma unroll
    for (int r = 0; r < 4; ++r) {
      #pragma unroll
      for (int off = 8; off; off >>= 1) rs[r] += __shfl_xor(rs[r], off);
      l_[r] = l_[r] * corr[r] + rs[r];
    }
    #pragma unroll
    for (int j = 0; j < 4; ++j)
      #pragma unroll
      for (int r = 0; r < 4; ++r) oacc[j][r] *= corr[r];

    #pragma unroll
    for (int j = 0; j < 4; ++j)
      #pragma unroll
      for (int r = 0; r < 4; ++r)
        Ps[wave][(kgrp * 4 + r) * 72 + j * 16 + rl] = f2b(s[j][r]);

    short8 pa0 = *(const short8*)&Ps[wave][rl * 72 + koff];
    short8 pa1 = *(const short8*)&Ps[wave][rl * 72 + 32 + koff];
    #pragma unroll
    for (int j = 0; j < 4; ++j) {
      short8 b0 = *(const short8*)&Vt[(j * 16 + rl) * 72 + koff];
      short8 b1 = *(const short8*)&Vt[(j * 16 + rl) * 72 + 32 + koff];
      oacc[j] = __builtin_amdgcn_mfma_f32_16x16x32_bf16(pa0, b0, oacc[j], 0, 0, 0);
      oacc[j] = __builtin_amdgcn_mfma_f32_16x16x32_bf16(pa1, b1, oacc[j], 0, 0, 0);
    }
    __syncthreads();
  }

  #pragma unroll
  for (int j = 0; j < 4; ++j)
    #pragma unroll
    for (int r = 0; r < 4; ++r) {
      int qrow = wave * 16 + kgrp * 4 + r;
      o[base + (size_t)(qt * 64 + qrow) * C_ + j * 16 + rl] = f2b(oacc[j][r] / l_[r]);
    }
}

// ------- MFMA BT GEMM, m97-style staging (VALIDATED r10) -------
// EPI: 0 = store bf16, 1 = relu bf16, 2 = fp32 residual +=, 3 = store fp32
template<int BM, int BN, int EPI>
__global__ __launch_bounds__(256) void gemm_bt(const unsigned short* __restrict__ A,
                                               const unsigned short* __restrict__ Bt,
                                               const float* __restrict__ bias,
                                               unsigned short* __restrict__ outb,
                                               float* __restrict__ outf,
                                               int M, int N, int K, int ldO,
                                               size_t zBt, size_t zOut) {
  constexpr int BK = 32;
  __shared__ __align__(16) unsigned short As[BM * BK];
  __shared__ __align__(16) unsigned short Bs[BN * BK];
  constexpr int FM = BM / 32, FN = BN / 32;

  int tid = threadIdx.x;
  int lane = tid & 63, wave = tid >> 6;
  int wr = wave >> 1, wc = wave & 1;
  int m0 = blockIdx.y * BM, n0 = blockIdx.x * BN;
  int rl = lane & 15, koff = (lane >> 4) * 8;
  Bt += zBt * blockIdx.z;

  int srow = lane >> 2, sseg = (lane & 3) * 8;

  f32x4 acc[FM][FN] = {};

  for (int k0 = 0; k0 < K; k0 += BK) {
    #pragma unroll
    for (int i = 0; i < BM / 64; ++i) {
      int r = i * 64 + wave * 16;
      gload16(&A[(size_t)(m0 + r + srow) * K + k0 + sseg], &As[r * BK]);
    }
    #pragma unroll
    for (int i = 0; i < BN / 64; ++i) {
      int r = i * 64 + wave * 16;
      gload16(&Bt[(size_t)(n0 + r + srow) * K + k0 + sseg], &Bs[r * BK]);
    }
    __syncthreads();

    short8 af[FM], bfr[FN];
    #pragma unroll
    for (int i = 0; i < FM; ++i)
      af[i] = *(const short8*)&As[(wr * (BM / 2) + i * 16 + rl) * BK + koff];
    #pragma unroll
    for (int j = 0; j < FN; ++j)
      bfr[j] = *(const short8*)&Bs[(wc * (BN / 2) + j * 16 + rl) * BK + koff];
    #pragma unroll
    for (int i = 0; i < FM; ++i)
      #pragma unroll
      for (int j = 0; j < FN; ++j)
        acc[i][j] = __builtin_amdgcn_mfma_f32_16x16x32_bf16(af[i], bfr[j], acc[i][j], 0, 0, 0);
    __syncthreads();
  }

  int rbase = (lane >> 4) * 4;
  #pragma unroll
  for (int i = 0; i < FM; ++i) {
    #pragma unroll
    for (int j = 0; j < FN; ++j) {
      #pragma unroll
      for (int r = 0; r < 4; ++r) {
        int m = m0 + wr * (BM / 2) + i * 16 + rbase + r;
        int n = n0 + wc * (BN / 2) + j * 16 + (lane & 15);
        float val = acc[i][j][r];
        if (bias) val += bias[n];
        if (EPI == 0)      (outb + zOut * blockIdx.z)[(size_t)m * ldO + n] = f2b(val);
        else if (EPI == 1) (outb + zOut * blockIdx.z)[(size_t)m * ldO + n] = f2b(fmaxf(val, 0.f));
        else if (EPI == 2) (outf + zOut * blockIdx.z)[(size_t)m * ldO + n] += val;
        else               (outf + zOut * blockIdx.z)[(size_t)m * ldO + n] = val;
      }
    }
  }
}

// ---------------- host-side launch ----------------
extern "C" void kernel_launch(void* const* d_in, const int* in_sizes, int n_in,
                              void* d_out, int out_size, void* d_ws, size_t ws_size,
                              hipStream_t stream) {
  const int*   idx  = (const int*)d_in[0];
  const float* tok  = (const float*)d_in[1];
  const float* pos  = (const float*)d_in[2];
  const float* Wq   = (const float*)d_in[3];
  const float* Wk   = (const float*)d_in[4];
  const float* Wv   = (const float*)d_in[5];
  const float* Wp   = (const float*)d_in[6];
  const float* bp   = (const float*)d_in[7];
  const float* ln1g = (const float*)d_in[8];
  const float* ln1b = (const float*)d_in[9];
  const float* ln2g = (const float*)d_in[10];
  const float* ln2b = (const float*)d_in[11];
  const float* W1   = (const float*)d_in[12];
  const float* b1   = (const float*)d_in[13];
  const float* W2   = (const float*)d_in[14];
  const float* b2   = (const float*)d_in[15];
  const float* lnfg = (const float*)d_in[16];
  const float* lnfb = (const float*)d_in[17];
  const float* Wh   = (const float*)d_in[18];
  const float* bh   = (const float*)d_in[19];

  float* out = (float*)d_out;   // fp32 logits

  // ---- workspace: x(6.3) + h(3.15) + qkvo/mid(12.6) + WT(9.8) = 31.9 MB ----
  const size_t MC = (size_t)M_ * C_;
  const size_t need = MC*4 + MC*2 + MC*2*4 + (size_t)NVC_*C_*2;
  if (ws_size < need) return;

  char* p = (char*)d_ws;
  float*          x   = (float*)p;            p += MC*4;
  unsigned short* h   = (unsigned short*)p;   p += MC*2;
  unsigned short* qb  = (unsigned short*)p;   p += MC*2;   // qb,kb,vb contiguous (z-batch)
  unsigned short* kb  = (unsigned short*)p;   p += MC*2;
  unsigned short* vb  = (unsigned short*)p;   p += MC*2;
  unsigned short* ob  = (unsigned short*)p;   p += MC*2;
  unsigned short* WT  = (unsigned short*)p;   p += (size_t)NVC_*C_*2;
  unsigned short* mid = qb;                   // [M][C4] bf16, overlays qkvo (dead)

  unsigned short* WqT = WT;                   // WqT,WkT,WvT contiguous (z-batch)
  unsigned short* WpT = WT + (size_t)3*C_*C_;
  unsigned short* W12T = WT;

  embed_kernel<<<M_, 256, 0, stream>>>(idx, tok, pos, x);

  for (int l = 0; l < L_; ++l) {
    size_t wo  = (size_t)l * C_ * C_;
    size_t wo4 = (size_t)l * C_ * C4_;
    size_t woq = (size_t)l * H_ * C_ * HS_;

    transpose_qkv<<<dim3(HS_/32, C_/32, 36), 256, 0, stream>>>(Wq + woq, Wk + woq, Wv + woq, WqT);
    transpose_f2b<<<dim3(C_/32, C_/32, 1), 256, 0, stream>>>(Wp + wo, WpT, C_, C_, 0, 0);

    ln_kernel<<<M_, 256, 0, stream>>>(x, ln1g + (size_t)l*C_, ln1b + (size_t)l*C_, h);
    gemm_bt<64,64,0><<<dim3(C_/64, M_/64, 3), 256, 0, stream>>>(h, WqT, nullptr, qb, nullptr,
                                                                M_, C_, C_, C_, (size_t)C_*C_, MC);
    attn_mfma<<<dim3(T_/64, B_*H_), 256, 0, stream>>>(qb, kb, vb, ob);
    gemm_bt<64,64,2><<<dim3(C_/64, M_/64), 256, 0, stream>>>(ob, WpT, bp + (size_t)l*C_, nullptr, x,
                                                             M_, C_, C_, C_, 0, 0);

    ln_kernel<<<M_, 256, 0, stream>>>(x, ln2g + (size_t)l*C_, ln2b + (size_t)l*C_, h);
    transpose_f2b<<<dim3(C4_/32, C_/32, 1), 256, 0, stream>>>(W1 + wo4, W12T, C4_, C_, 0, 0);
    gemm_bt<128,128,1><<<dim3(C4_/128, M_/128), 256, 0, stream>>>(h, W12T, b1 + (size_t)l*C4_, mid, nullptr,
                                                                  M_, C4_, C_, C4_, 0, 0);
    transpose_f2b<<<dim3(C_/32, C4_/32, 1), 256, 0, stream>>>(W2 + wo4, W12T, C_, C4_, 0, 0);
    gemm_bt<64,64,2><<<dim3(C_/64, M_/64), 256, 0, stream>>>(mid, W12T, b2 + (size_t)l*C_, nullptr, x,
                                                             M_, C_, C4_, C_, 0, 0);
  }

  // ---- final LN + chunked lm_head (fp32 store) ----
  ln_kernel<<<M_, 256, 0, stream>>>(x, lnfg, lnfb, h);
  for (int ci = 0; ci < V_/NVC_; ++ci) {
    transpose_f2b<<<dim3(NVC_/32, C_/32, 1), 256, 0, stream>>>(Wh + (size_t)ci*NVC_, WT, V_, C_, 0, 0);
    gemm_bt<128,128,3><<<dim3(NVC_/128, M_/128), 256, 0, stream>>>(
        h, WT, bh + (size_t)ci*NVC_, nullptr, out + (size_t)ci*NVC_, M_, NVC_, C_, V_, 0, 0);
  }
}

// Round 12
// 1361.904 us; speedup vs baseline: 10.2338x; 1.1597x over previous
//
#include <hip/hip_runtime.h>

// ---------------- problem constants ----------------
#define B_ 2
#define T_ 1024
#define C_ 768
#define H_ 12
#define L_ 6
#define V_ 32000
#define HS_ 64
#define M_ (B_*T_)            // 2048 token rows
#define C4_ (4*C_)            // 3072
#define NVC_ 6400             // lm_head column chunk (fallback path)

typedef __attribute__((ext_vector_type(8))) short short8;
typedef __attribute__((ext_vector_type(4))) float f32x4;

__device__ __forceinline__ float b2f(unsigned short u) {
  union { unsigned int i; float f; } x; x.i = ((unsigned int)u) << 16; return x.f;
}
__device__ __forceinline__ unsigned short f2b(float f) {
  unsigned int u = __builtin_bit_cast(unsigned int, f);
  u += 0x7fffu + ((u >> 16) & 1u);
  return (unsigned short)(u >> 16);
}

// async global->LDS, 16B per lane; LDS dest wave-uniform, lanes write dest + lane*16
__device__ __forceinline__ void gload16(const unsigned short* g, unsigned short* l) {
  __builtin_amdgcn_global_load_lds(
      (const __attribute__((address_space(1))) unsigned int*)g,
      (__attribute__((address_space(3))) unsigned int*)l, 16, 0, 0);
}

// -------- transpose + fp32->bf16: out[c][r] = bf16(in[r][c]), z-batched (VALIDATED) --------
__global__ __launch_bounds__(256) void transpose_f2b(const float* __restrict__ in,
                                                     unsigned short* __restrict__ out,
                                                     int ldi, int ldo, size_t zi, size_t zo) {
  __shared__ unsigned short tile[32][33];
  in  += zi * blockIdx.z;
  out += zo * blockIdx.z;
  int c0 = blockIdx.x * 32, r0 = blockIdx.y * 32;
  int tx = threadIdx.x & 31, ty = threadIdx.x >> 5;   // 32 x 8
  #pragma unroll
  for (int j = 0; j < 32; j += 8)
    tile[ty + j][tx] = f2b(in[(size_t)(r0 + ty + j) * ldi + c0 + tx]);
  __syncthreads();
  #pragma unroll
  for (int j = 0; j < 32; j += 8)
    out[(size_t)(c0 + ty + j) * ldo + r0 + tx] = tile[tx][ty + j];
}

// -------- merged QKV+P transpose: z in [0,48) --------
// z<36: {Wq,Wk,Wv}[head] [C][HS] -> [HS][C];  z>=36: Wp 64-col chunk [C][64] -> rows of WpT
__global__ __launch_bounds__(256) void transpose_qkvp(const float* __restrict__ Wq,
                                                      const float* __restrict__ Wk,
                                                      const float* __restrict__ Wv,
                                                      const float* __restrict__ Wp,
                                                      unsigned short* __restrict__ out) {
  __shared__ unsigned short tile[32][33];
  int z = blockIdx.z;
  const float* in; unsigned short* o; int ldi; int cbase;
  if (z < 36) {
    int which = z / H_, hh = z % H_;
    in = (which == 0 ? Wq : which == 1 ? Wk : Wv) + (size_t)hh * C_ * HS_;
    o = out + (size_t)which * C_ * C_ + (size_t)hh * HS_ * C_;
    ldi = HS_; cbase = 0;
  } else {
    int ch = z - 36;
    in = Wp; ldi = C_; cbase = ch * 64;
    o = out + (size_t)3 * C_ * C_ + (size_t)ch * 64 * C_;
  }
  int c0 = blockIdx.x * 32, r0 = blockIdx.y * 32;
  int tx = threadIdx.x & 31, ty = threadIdx.x >> 5;
  #pragma unroll
  for (int j = 0; j < 32; j += 8)
    tile[ty + j][tx] = f2b(in[(size_t)(r0 + ty + j) * ldi + cbase + c0 + tx]);
  __syncthreads();
  #pragma unroll
  for (int j = 0; j < 32; j += 8)
    o[(size_t)(c0 + ty + j) * C_ + r0 + tx] = tile[tx][ty + j];
}

// ---------------- embedding: x = tok_emb[idx] + pos_emb (fp32) ----------------
__global__ __launch_bounds__(256) void embed_kernel(const int* __restrict__ idx,
                                                    const float* __restrict__ tok,
                                                    const float* __restrict__ pos,
                                                    float* __restrict__ x) {
  int m = blockIdx.x;
  int t = m & (T_ - 1);
  int tk = idx[m];
  #pragma unroll
  for (int i = 0; i < 3; ++i) {
    int c = threadIdx.x + i * 256;
    x[(size_t)m * C_ + c] = tok[(size_t)tk * C_ + c] + pos[(size_t)t * C_ + c];
  }
}

// ---------------- layernorm: h(bf16) = LN(x)*g + b   (x,g,b fp32) ----------------
__global__ __launch_bounds__(256) void ln_kernel(const float* __restrict__ x,
                                                 const float* __restrict__ g,
                                                 const float* __restrict__ bta,
                                                 unsigned short* __restrict__ h) {
  int m = blockIdx.x;
  const float* xr = x + (size_t)m * C_;
  float v[3], s = 0.f, ss = 0.f;
  #pragma unroll
  for (int i = 0; i < 3; ++i) {
    v[i] = xr[threadIdx.x + i * 256];
    s += v[i]; ss += v[i] * v[i];
  }
  #pragma unroll
  for (int off = 32; off; off >>= 1) { s += __shfl_xor(s, off); ss += __shfl_xor(ss, off); }
  __shared__ float red[8];
  int wave = threadIdx.x >> 6, lane = threadIdx.x & 63;
  if (lane == 0) { red[wave] = s; red[4 + wave] = ss; }
  __syncthreads();
  s  = red[0] + red[1] + red[2] + red[3];
  ss = red[4] + red[5] + red[6] + red[7];
  float mean = s * (1.f / C_);
  float var  = fmaxf(ss * (1.f / C_) - mean * mean, 0.f);
  float rstd = rsqrtf(var + 1e-5f);
  #pragma unroll
  for (int i = 0; i < 3; ++i) {
    int c = threadIdx.x + i * 256;
    h[(size_t)m * C_ + c] = f2b((v[i] - mean) * rstd * g[c] + bta[c]);
  }
}

// ---------------- MFMA flash attention (r9 math; + reg-prefetch K/V, setprio, no Q-LDS) ----------------
__global__ __launch_bounds__(256) void attn_mfma(const unsigned short* __restrict__ q,
                                                 const unsigned short* __restrict__ k,
                                                 const unsigned short* __restrict__ v,
                                                 unsigned short* __restrict__ o) {
  const float scale = 0.03608439182435161f;   // 768^-0.5 (reference scales by C, not HS)
  __shared__ __align__(16) unsigned short Ks[64 * 72];
  __shared__ __align__(16) unsigned short Vt[64 * 72];   // transposed: [d][kk]
  __shared__ __align__(16) unsigned short Ps[4][16 * 72]; // per-wave P

  int tid = threadIdx.x;
  int lane = tid & 63, wave = tid >> 6;
  int rl = lane & 15, kgrp = lane >> 4, koff = kgrp * 8;
  int qt = blockIdx.x;
  int bh = blockIdx.y;
  int hh = bh % H_, bb = bh / H_;
  size_t base = (size_t)bb * T_ * C_ + (size_t)hh * HS_;

  // Q fragments straight from global (L2-hot, once per block)
  short8 qf0 = *(const short8*)&q[base + (size_t)(qt * 64 + wave * 16 + rl) * C_ + koff];
  short8 qf1 = *(const short8*)&q[base + (size_t)(qt * 64 + wave * 16 + rl) * C_ + 32 + koff];

  float m_[4], l_[4];
  f32x4 oacc[4];
  #pragma unroll
  for (int r = 0; r < 4; ++r) { m_[r] = -INFINITY; l_[r] = 0.f; }
  #pragma unroll
  for (int j = 0; j < 4; ++j) oacc[j] = (f32x4){0.f, 0.f, 0.f, 0.f};

  // prefetch tile 0 into regs
  short8 kreg[2], vreg[2];
  #pragma unroll
  for (int i = 0; i < 2; ++i) {
    int e = tid + i * 256;
    kreg[i] = *(const short8*)&k[base + (size_t)(e >> 3) * C_ + (e & 7) * 8];
    vreg[i] = *(const short8*)&v[base + (size_t)(e >> 3) * C_ + (e & 7) * 8];
  }

  for (int kt = 0; kt <= qt; ++kt) {
    // regs -> LDS
    #pragma unroll
    for (int i = 0; i < 2; ++i) {
      int e = tid + i * 256, row = e >> 3, c8 = e & 7;
      *(short8*)&Ks[row * 72 + c8 * 8] = kreg[i];
    }
    #pragma unroll
    for (int i = 0; i < 2; ++i) {
      int e = tid + i * 256, kk = e >> 3, d8 = (e & 7) * 8;
      short8 vv = vreg[i];
      #pragma unroll
      for (int t2 = 0; t2 < 8; ++t2) {
        int ii = (t2 + tid) & 7;
        Vt[(d8 + ii) * 72 + kk] = vv[ii];
      }
    }
    __syncthreads();

    // issue next-tile loads (hide under MFMA+softmax below)
    if (kt < qt) {
      #pragma unroll
      for (int i = 0; i < 2; ++i) {
        int e = tid + i * 256;
        kreg[i] = *(const short8*)&k[base + (size_t)((kt + 1) * 64 + (e >> 3)) * C_ + (e & 7) * 8];
        vreg[i] = *(const short8*)&v[base + (size_t)((kt + 1) * 64 + (e >> 3)) * C_ + (e & 7) * 8];
      }
    }

    f32x4 s[4];
    #pragma unroll
    for (int j = 0; j < 4; ++j) s[j] = (f32x4){0.f, 0.f, 0.f, 0.f};
    __builtin_amdgcn_s_setprio(1);
    #pragma unroll
    for (int j = 0; j < 4; ++j) {
      short8 b0 = *(const short8*)&Ks[(j * 16 + rl) * 72 + koff];
      short8 b1 = *(const short8*)&Ks[(j * 16 + rl) * 72 + 32 + koff];
      s[j] = __builtin_amdgcn_mfma_f32_16x16x32_bf16(qf0, b0, s[j], 0, 0, 0);
      s[j] = __builtin_amdgcn_mfma_f32_16x16x32_bf16(qf1, b1, s[j], 0, 0, 0);
    }
    __builtin_amdgcn_s_setprio(0);

    bool diag = (kt == qt);
    #pragma unroll
    for (int j = 0; j < 4; ++j)
      #pragma unroll
      for (int r = 0; r < 4; ++r) {
        float sv = s[j][r] * scale;
        if (diag) {
          int urow = j * 16 + rl, qrow = wave * 16 + kgrp * 4 + r;
          if (urow > qrow) sv = -INFINITY;
        }
        s[j][r] = sv;
      }

    float corr[4], rs[4];
    #pragma unroll
    for (int r = 0; r < 4; ++r) {
      float mrow = fmaxf(fmaxf(s[0][r], s[1][r]), fmaxf(s[2][r], s[3][r]));
      #pragma unroll
      for (int off = 8; off; off >>= 1) mrow = fmaxf(mrow, __shfl_xor(mrow, off));
      float mnew = fmaxf(m_[r], mrow);
      corr[r] = __expf(m_[r] - mnew);
      m_[r] = mnew;
    }
    #pragma unroll
    for (int r = 0; r < 4; ++r) rs[r] = 0.f;
    #pragma unroll
    for (int j = 0; j < 4; ++j)
      #pragma unroll
      for (int r = 0; r < 4; ++r) {
        float p = (s[j][r] == -INFINITY) ? 0.f : __expf(s[j][r] - m_[r]);
        s[j][r] = p;
        rs[r] += p;
      }
    #pragma unroll
    for (int r = 0; r < 4; ++r) {
      #pragma unroll
      for (int off = 8; off; off >>= 1) rs[r] += __shfl_xor(rs[r], off);
      l_[r] = l_[r] * corr[r] + rs[r];
    }
    #pragma unroll
    for (int j = 0; j < 4; ++j)
      #pragma unroll
      for (int r = 0; r < 4; ++r) oacc[j][r] *= corr[r];

    #pragma unroll
    for (int j = 0; j < 4; ++j)
      #pragma unroll
      for (int r = 0; r < 4; ++r)
        Ps[wave][(kgrp * 4 + r) * 72 + j * 16 + rl] = f2b(s[j][r]);

    short8 pa0 = *(const short8*)&Ps[wave][rl * 72 + koff];
    short8 pa1 = *(const short8*)&Ps[wave][rl * 72 + 32 + koff];
    __builtin_amdgcn_s_setprio(1);
    #pragma unroll
    for (int j = 0; j < 4; ++j) {
      short8 b0 = *(const short8*)&Vt[(j * 16 + rl) * 72 + koff];
      short8 b1 = *(const short8*)&Vt[(j * 16 + rl) * 72 + 32 + koff];
      oacc[j] = __builtin_amdgcn_mfma_f32_16x16x32_bf16(pa0, b0, oacc[j], 0, 0, 0);
      oacc[j] = __builtin_amdgcn_mfma_f32_16x16x32_bf16(pa1, b1, oacc[j], 0, 0, 0);
    }
    __builtin_amdgcn_s_setprio(0);
    __syncthreads();
  }

  #pragma unroll
  for (int j = 0; j < 4; ++j)
    #pragma unroll
    for (int r = 0; r < 4; ++r) {
      int qrow = wave * 16 + kgrp * 4 + r;
      o[base + (size_t)(qt * 64 + qrow) * C_ + j * 16 + rl] = f2b(oacc[j][r] / l_[r]);
    }
}

// ------- MFMA BT GEMM, m97-style staging (VALIDATED r10); MFAST = m-tile on blockIdx.x -------
// EPI: 0 = store bf16, 1 = relu bf16, 2 = fp32 residual +=, 3 = store fp32
template<int BM, int BN, int EPI, bool MFAST>
__global__ __launch_bounds__(256) void gemm_bt(const unsigned short* __restrict__ A,
                                               const unsigned short* __restrict__ Bt,
                                               const float* __restrict__ bias,
                                               unsigned short* __restrict__ outb,
                                               float* __restrict__ outf,
                                               int M, int N, int K, int ldO,
                                               size_t zBt, size_t zOut) {
  constexpr int BK = 32;
  __shared__ __align__(16) unsigned short As[BM * BK];
  __shared__ __align__(16) unsigned short Bs[BN * BK];
  constexpr int FM = BM / 32, FN = BN / 32;

  int tid = threadIdx.x;
  int lane = tid & 63, wave = tid >> 6;
  int wr = wave >> 1, wc = wave & 1;
  int m0 = (MFAST ? blockIdx.x : blockIdx.y) * BM;
  int n0 = (MFAST ? blockIdx.y : blockIdx.x) * BN;
  int rl = lane & 15, koff = (lane >> 4) * 8;
  Bt += zBt * blockIdx.z;

  int srow = lane >> 2, sseg = (lane & 3) * 8;

  f32x4 acc[FM][FN] = {};

  for (int k0 = 0; k0 < K; k0 += BK) {
    #pragma unroll
    for (int i = 0; i < BM / 64; ++i) {
      int r = i * 64 + wave * 16;
      gload16(&A[(size_t)(m0 + r + srow) * K + k0 + sseg], &As[r * BK]);
    }
    #pragma unroll
    for (int i = 0; i < BN / 64; ++i) {
      int r = i * 64 + wave * 16;
      gload16(&Bt[(size_t)(n0 + r + srow) * K + k0 + sseg], &Bs[r * BK]);
    }
    __syncthreads();

    short8 af[FM], bfr[FN];
    #pragma unroll
    for (int i = 0; i < FM; ++i)
      af[i] = *(const short8*)&As[(wr * (BM / 2) + i * 16 + rl) * BK + koff];
    #pragma unroll
    for (int j = 0; j < FN; ++j)
      bfr[j] = *(const short8*)&Bs[(wc * (BN / 2) + j * 16 + rl) * BK + koff];
    #pragma unroll
    for (int i = 0; i < FM; ++i)
      #pragma unroll
      for (int j = 0; j < FN; ++j)
        acc[i][j] = __builtin_amdgcn_mfma_f32_16x16x32_bf16(af[i], bfr[j], acc[i][j], 0, 0, 0);
    __syncthreads();
  }

  int rbase = (lane >> 4) * 4;
  #pragma unroll
  for (int i = 0; i < FM; ++i) {
    #pragma unroll
    for (int j = 0; j < FN; ++j) {
      #pragma unroll
      for (int r = 0; r < 4; ++r) {
        int m = m0 + wr * (BM / 2) + i * 16 + rbase + r;
        int n = n0 + wc * (BN / 2) + j * 16 + (lane & 15);
        float val = acc[i][j][r];
        if (bias) val += bias[n];
        if (EPI == 0)      (outb + zOut * blockIdx.z)[(size_t)m * ldO + n] = f2b(val);
        else if (EPI == 1) (outb + zOut * blockIdx.z)[(size_t)m * ldO + n] = f2b(fmaxf(val, 0.f));
        else if (EPI == 2) (outf + zOut * blockIdx.z)[(size_t)m * ldO + n] += val;
        else               (outf + zOut * blockIdx.z)[(size_t)m * ldO + n] = val;
      }
    }
  }
}

// ---------------- host-side launch ----------------
extern "C" void kernel_launch(void* const* d_in, const int* in_sizes, int n_in,
                              void* d_out, int out_size, void* d_ws, size_t ws_size,
                              hipStream_t stream) {
  const int*   idx  = (const int*)d_in[0];
  const float* tok  = (const float*)d_in[1];
  const float* pos  = (const float*)d_in[2];
  const float* Wq   = (const float*)d_in[3];
  const float* Wk   = (const float*)d_in[4];
  const float* Wv   = (const float*)d_in[5];
  const float* Wp   = (const float*)d_in[6];
  const float* bp   = (const float*)d_in[7];
  const float* ln1g = (const float*)d_in[8];
  const float* ln1b = (const float*)d_in[9];
  const float* ln2g = (const float*)d_in[10];
  const float* ln2b = (const float*)d_in[11];
  const float* W1   = (const float*)d_in[12];
  const float* b1   = (const float*)d_in[13];
  const float* W2   = (const float*)d_in[14];
  const float* b2   = (const float*)d_in[15];
  const float* lnfg = (const float*)d_in[16];
  const float* lnfb = (const float*)d_in[17];
  const float* Wh   = (const float*)d_in[18];
  const float* bh   = (const float*)d_in[19];

  float* out = (float*)d_out;   // fp32 logits

  const size_t MC = (size_t)M_ * C_;
  const size_t fixed = MC*4 + MC*2 + MC*2*4;                 // x, h, qkvo region
  const size_t need_chunk = fixed + (size_t)NVC_*C_*2;       // 31.9 MB (proven available)
  const size_t need_full  = fixed + (size_t)V_*C_*2;         // 71.2 MB (runtime-checked)
  if (ws_size < need_chunk) return;
  const bool full_head = (ws_size >= need_full);

  char* p = (char*)d_ws;
  float*          x   = (float*)p;            p += MC*4;
  unsigned short* h   = (unsigned short*)p;   p += MC*2;
  unsigned short* qb  = (unsigned short*)p;   p += MC*2;   // qb,kb,vb contiguous (z-batch)
  unsigned short* kb  = (unsigned short*)p;   p += MC*2;
  unsigned short* vb  = (unsigned short*)p;   p += MC*2;
  unsigned short* ob  = (unsigned short*)p;   p += MC*2;
  unsigned short* WT  = (unsigned short*)p;                // 9.8 MB (chunk) or 49 MB (full)
  unsigned short* mid = qb;                   // [M][C4] bf16, overlays qkvo (dead)

  unsigned short* WqT = WT;                   // WqT,WkT,WvT,WpT contiguous
  unsigned short* WpT = WT + (size_t)3*C_*C_;
  unsigned short* W12T = WT;

  embed_kernel<<<M_, 256, 0, stream>>>(idx, tok, pos, x);

  for (int l = 0; l < L_; ++l) {
    size_t wo  = (size_t)l * C_ * C_;
    size_t wo4 = (size_t)l * C_ * C4_;
    size_t woq = (size_t)l * H_ * C_ * HS_;

    transpose_qkvp<<<dim3(HS_/32, C_/32, 48), 256, 0, stream>>>(Wq + woq, Wk + woq, Wv + woq, Wp + wo, WqT);

    ln_kernel<<<M_, 256, 0, stream>>>(x, ln1g + (size_t)l*C_, ln1b + (size_t)l*C_, h);
    gemm_bt<64,64,0,false><<<dim3(C_/64, M_/64, 3), 256, 0, stream>>>(h, WqT, nullptr, qb, nullptr,
                                                                      M_, C_, C_, C_, (size_t)C_*C_, MC);
    attn_mfma<<<dim3(T_/64, B_*H_), 256, 0, stream>>>(qb, kb, vb, ob);
    gemm_bt<64,64,2,false><<<dim3(C_/64, M_/64), 256, 0, stream>>>(ob, WpT, bp + (size_t)l*C_, nullptr, x,
                                                                   M_, C_, C_, C_, 0, 0);

    ln_kernel<<<M_, 256, 0, stream>>>(x, ln2g + (size_t)l*C_, ln2b + (size_t)l*C_, h);
    transpose_f2b<<<dim3(C4_/32, C_/32, 1), 256, 0, stream>>>(W1 + wo4, W12T, C4_, C_, 0, 0);
    gemm_bt<128,128,1,true><<<dim3(M_/128, C4_/128), 256, 0, stream>>>(h, W12T, b1 + (size_t)l*C4_, mid, nullptr,
                                                                       M_, C4_, C_, C4_, 0, 0);
    transpose_f2b<<<dim3(C_/32, C4_/32, 1), 256, 0, stream>>>(W2 + wo4, W12T, C_, C4_, 0, 0);
    gemm_bt<64,64,2,true><<<dim3(M_/64, C_/64), 256, 0, stream>>>(mid, W12T, b2 + (size_t)l*C_, nullptr, x,
                                                                  M_, C_, C4_, C_, 0, 0);
  }

  // ---- final LN + lm_head (fp32 store) ----
  ln_kernel<<<M_, 256, 0, stream>>>(x, lnfg, lnfb, h);
  if (full_head) {
    transpose_f2b<<<dim3(V_/32, C_/32, 1), 256, 0, stream>>>(Wh, WT, V_, C_, 0, 0);
    gemm_bt<128,128,3,true><<<dim3(M_/128, V_/128), 256, 0, stream>>>(
        h, WT, bh, nullptr, out, M_, V_, C_, V_, 0, 0);
  } else {
    for (int ci = 0; ci < V_/NVC_; ++ci) {
      transpose_f2b<<<dim3(NVC_/32, C_/32, 1), 256, 0, stream>>>(Wh + (size_t)ci*NVC_, WT, V_, C_, 0, 0);
      gemm_bt<128,128,3,true><<<dim3(M_/128, NVC_/128), 256, 0, stream>>>(
          h, WT, bh + (size_t)ci*NVC_, nullptr, out + (size_t)ci*NVC_, M_, NVC_, C_, V_, 0, 0);
    }
  }
}

// Round 13
// 1309.589 us; speedup vs baseline: 10.6426x; 1.0399x over previous
//
#include <hip/hip_runtime.h>

// ---------------- problem constants ----------------
#define B_ 2
#define T_ 1024
#define C_ 768
#define H_ 12
#define L_ 6
#define V_ 32000
#define HS_ 64
#define M_ (B_*T_)            // 2048 token rows
#define C4_ (4*C_)            // 3072
#define NVC_ 6400             // lm_head column chunk (fallback path)

typedef __attribute__((ext_vector_type(8))) short short8;
typedef __attribute__((ext_vector_type(4))) float f32x4;

__device__ __forceinline__ float b2f(unsigned short u) {
  union { unsigned int i; float f; } x; x.i = ((unsigned int)u) << 16; return x.f;
}
__device__ __forceinline__ unsigned short f2b(float f) {
  unsigned int u = __builtin_bit_cast(unsigned int, f);
  u += 0x7fffu + ((u >> 16) & 1u);
  return (unsigned short)(u >> 16);
}

// async global->LDS, 16B per lane; LDS dest wave-uniform, lanes write dest + lane*16
__device__ __forceinline__ void gload16(const unsigned short* g, unsigned short* l) {
  __builtin_amdgcn_global_load_lds(
      (const __attribute__((address_space(1))) unsigned int*)g,
      (__attribute__((address_space(3))) unsigned int*)l, 16, 0, 0);
}

// -------- transpose + fp32->bf16: out[c][r] = bf16(in[r][c]), z-batched (VALIDATED) --------
__global__ __launch_bounds__(256) void transpose_f2b(const float* __restrict__ in,
                                                     unsigned short* __restrict__ out,
                                                     int ldi, int ldo, size_t zi, size_t zo) {
  __shared__ unsigned short tile[32][33];
  in  += zi * blockIdx.z;
  out += zo * blockIdx.z;
  int c0 = blockIdx.x * 32, r0 = blockIdx.y * 32;
  int tx = threadIdx.x & 31, ty = threadIdx.x >> 5;   // 32 x 8
  #pragma unroll
  for (int j = 0; j < 32; j += 8)
    tile[ty + j][tx] = f2b(in[(size_t)(r0 + ty + j) * ldi + c0 + tx]);
  __syncthreads();
  #pragma unroll
  for (int j = 0; j < 32; j += 8)
    out[(size_t)(c0 + ty + j) * ldo + r0 + tx] = tile[tx][ty + j];
}

// -------- merged QKV+P transpose: z in [0,48) --------
__global__ __launch_bounds__(256) void transpose_qkvp(const float* __restrict__ Wq,
                                                      const float* __restrict__ Wk,
                                                      const float* __restrict__ Wv,
                                                      const float* __restrict__ Wp,
                                                      unsigned short* __restrict__ out) {
  __shared__ unsigned short tile[32][33];
  int z = blockIdx.z;
  const float* in; unsigned short* o; int ldi; int cbase;
  if (z < 36) {
    int which = z / H_, hh = z % H_;
    in = (which == 0 ? Wq : which == 1 ? Wk : Wv) + (size_t)hh * C_ * HS_;
    o = out + (size_t)which * C_ * C_ + (size_t)hh * HS_ * C_;
    ldi = HS_; cbase = 0;
  } else {
    int ch = z - 36;
    in = Wp; ldi = C_; cbase = ch * 64;
    o = out + (size_t)3 * C_ * C_ + (size_t)ch * 64 * C_;
  }
  int c0 = blockIdx.x * 32, r0 = blockIdx.y * 32;
  int tx = threadIdx.x & 31, ty = threadIdx.x >> 5;
  #pragma unroll
  for (int j = 0; j < 32; j += 8)
    tile[ty + j][tx] = f2b(in[(size_t)(r0 + ty + j) * ldi + cbase + c0 + tx]);
  __syncthreads();
  #pragma unroll
  for (int j = 0; j < 32; j += 8)
    o[(size_t)(c0 + ty + j) * C_ + r0 + tx] = tile[tx][ty + j];
}

// ---------------- embedding ----------------
__global__ __launch_bounds__(256) void embed_kernel(const int* __restrict__ idx,
                                                    const float* __restrict__ tok,
                                                    const float* __restrict__ pos,
                                                    float* __restrict__ x) {
  int m = blockIdx.x;
  int t = m & (T_ - 1);
  int tk = idx[m];
  #pragma unroll
  for (int i = 0; i < 3; ++i) {
    int c = threadIdx.x + i * 256;
    x[(size_t)m * C_ + c] = tok[(size_t)tk * C_ + c] + pos[(size_t)t * C_ + c];
  }
}

// ---------------- layernorm ----------------
__global__ __launch_bounds__(256) void ln_kernel(const float* __restrict__ x,
                                                 const float* __restrict__ g,
                                                 const float* __restrict__ bta,
                                                 unsigned short* __restrict__ h) {
  int m = blockIdx.x;
  const float* xr = x + (size_t)m * C_;
  float v[3], s = 0.f, ss = 0.f;
  #pragma unroll
  for (int i = 0; i < 3; ++i) {
    v[i] = xr[threadIdx.x + i * 256];
    s += v[i]; ss += v[i] * v[i];
  }
  #pragma unroll
  for (int off = 32; off; off >>= 1) { s += __shfl_xor(s, off); ss += __shfl_xor(ss, off); }
  __shared__ float red[8];
  int wave = threadIdx.x >> 6, lane = threadIdx.x & 63;
  if (lane == 0) { red[wave] = s; red[4 + wave] = ss; }
  __syncthreads();
  s  = red[0] + red[1] + red[2] + red[3];
  ss = red[4] + red[5] + red[6] + red[7];
  float mean = s * (1.f / C_);
  float var  = fmaxf(ss * (1.f / C_) - mean * mean, 0.f);
  float rstd = rsqrtf(var + 1e-5f);
  #pragma unroll
  for (int i = 0; i < 3; ++i) {
    int c = threadIdx.x + i * 256;
    h[(size_t)m * C_ + c] = f2b((v[i] - mean) * rstd * g[c] + bta[c]);
  }
}

// ---------------- MFMA flash attention (r12 math; paired q-tiles for load balance) ----------------
// Block bx in [0,8): processes qt = bx and qt = 15-bx -> uniform 17 tile-steps per block.
__global__ __launch_bounds__(256) void attn_mfma(const unsigned short* __restrict__ q,
                                                 const unsigned short* __restrict__ k,
                                                 const unsigned short* __restrict__ v,
                                                 unsigned short* __restrict__ o) {
  const float scale = 0.03608439182435161f;   // 768^-0.5 (reference scales by C, not HS)
  __shared__ __align__(16) unsigned short Ks[64 * 72];
  __shared__ __align__(16) unsigned short Vt[64 * 72];
  __shared__ __align__(16) unsigned short Ps[4][16 * 72];

  int tid = threadIdx.x;
  int lane = tid & 63, wave = tid >> 6;
  int rl = lane & 15, kgrp = lane >> 4, koff = kgrp * 8;
  int bh = blockIdx.y;
  int hh = bh % H_, bb = bh / H_;
  size_t base = (size_t)bb * T_ * C_ + (size_t)hh * HS_;

  for (int pass = 0; pass < 2; ++pass) {
    int qt = pass ? (15 - (int)blockIdx.x) : (int)blockIdx.x;

    short8 qf0 = *(const short8*)&q[base + (size_t)(qt * 64 + wave * 16 + rl) * C_ + koff];
    short8 qf1 = *(const short8*)&q[base + (size_t)(qt * 64 + wave * 16 + rl) * C_ + 32 + koff];

    float m_[4], l_[4];
    f32x4 oacc[4];
    #pragma unroll
    for (int r = 0; r < 4; ++r) { m_[r] = -INFINITY; l_[r] = 0.f; }
    #pragma unroll
    for (int j = 0; j < 4; ++j) oacc[j] = (f32x4){0.f, 0.f, 0.f, 0.f};

    short8 kreg[2], vreg[2];
    #pragma unroll
    for (int i = 0; i < 2; ++i) {
      int e = tid + i * 256;
      kreg[i] = *(const short8*)&k[base + (size_t)(e >> 3) * C_ + (e & 7) * 8];
      vreg[i] = *(const short8*)&v[base + (size_t)(e >> 3) * C_ + (e & 7) * 8];
    }

    for (int kt = 0; kt <= qt; ++kt) {
      #pragma unroll
      for (int i = 0; i < 2; ++i) {
        int e = tid + i * 256, row = e >> 3, c8 = e & 7;
        *(short8*)&Ks[row * 72 + c8 * 8] = kreg[i];
      }
      #pragma unroll
      for (int i = 0; i < 2; ++i) {
        int e = tid + i * 256, kk = e >> 3, d8 = (e & 7) * 8;
        short8 vv = vreg[i];
        #pragma unroll
        for (int t2 = 0; t2 < 8; ++t2) {
          int ii = (t2 + tid) & 7;
          Vt[(d8 + ii) * 72 + kk] = vv[ii];
        }
      }
      __syncthreads();

      if (kt < qt) {
        #pragma unroll
        for (int i = 0; i < 2; ++i) {
          int e = tid + i * 256;
          kreg[i] = *(const short8*)&k[base + (size_t)((kt + 1) * 64 + (e >> 3)) * C_ + (e & 7) * 8];
          vreg[i] = *(const short8*)&v[base + (size_t)((kt + 1) * 64 + (e >> 3)) * C_ + (e & 7) * 8];
        }
      }

      f32x4 s[4];
      #pragma unroll
      for (int j = 0; j < 4; ++j) s[j] = (f32x4){0.f, 0.f, 0.f, 0.f};
      __builtin_amdgcn_s_setprio(1);
      #pragma unroll
      for (int j = 0; j < 4; ++j) {
        short8 b0 = *(const short8*)&Ks[(j * 16 + rl) * 72 + koff];
        short8 b1 = *(const short8*)&Ks[(j * 16 + rl) * 72 + 32 + koff];
        s[j] = __builtin_amdgcn_mfma_f32_16x16x32_bf16(qf0, b0, s[j], 0, 0, 0);
        s[j] = __builtin_amdgcn_mfma_f32_16x16x32_bf16(qf1, b1, s[j], 0, 0, 0);
      }
      __builtin_amdgcn_s_setprio(0);

      bool diag = (kt == qt);
      #pragma unroll
      for (int j = 0; j < 4; ++j)
        #pragma unroll
        for (int r = 0; r < 4; ++r) {
          float sv = s[j][r] * scale;
          if (diag) {
            int urow = j * 16 + rl, qrow = wave * 16 + kgrp * 4 + r;
            if (urow > qrow) sv = -INFINITY;
          }
          s[j][r] = sv;
        }

      float corr[4], rs[4];
      #pragma unroll
      for (int r = 0; r < 4; ++r) {
        float mrow = fmaxf(fmaxf(s[0][r], s[1][r]), fmaxf(s[2][r], s[3][r]));
        #pragma unroll
        for (int off = 8; off; off >>= 1) mrow = fmaxf(mrow, __shfl_xor(mrow, off));
        float mnew = fmaxf(m_[r], mrow);
        corr[r] = __expf(m_[r] - mnew);
        m_[r] = mnew;
      }
      #pragma unroll
      for (int r = 0; r < 4; ++r) rs[r] = 0.f;
      #pragma unroll
      for (int j = 0; j < 4; ++j)
        #pragma unroll
        for (int r = 0; r < 4; ++r) {
          float p = (s[j][r] == -INFINITY) ? 0.f : __expf(s[j][r] - m_[r]);
          s[j][r] = p;
          rs[r] += p;
        }
      #pragma unroll
      for (int r = 0; r < 4; ++r) {
        #pragma unroll
        for (int off = 8; off; off >>= 1) rs[r] += __shfl_xor(rs[r], off);
        l_[r] = l_[r] * corr[r] + rs[r];
      }
      #pragma unroll
      for (int j = 0; j < 4; ++j)
        #pragma unroll
        for (int r = 0; r < 4; ++r) oacc[j][r] *= corr[r];

      #pragma unroll
      for (int j = 0; j < 4; ++j)
        #pragma unroll
        for (int r = 0; r < 4; ++r)
          Ps[wave][(kgrp * 4 + r) * 72 + j * 16 + rl] = f2b(s[j][r]);

      short8 pa0 = *(const short8*)&Ps[wave][rl * 72 + koff];
      short8 pa1 = *(const short8*)&Ps[wave][rl * 72 + 32 + koff];
      __builtin_amdgcn_s_setprio(1);
      #pragma unroll
      for (int j = 0; j < 4; ++j) {
        short8 b0 = *(const short8*)&Vt[(j * 16 + rl) * 72 + koff];
        short8 b1 = *(const short8*)&Vt[(j * 16 + rl) * 72 + 32 + koff];
        oacc[j] = __builtin_amdgcn_mfma_f32_16x16x32_bf16(pa0, b0, oacc[j], 0, 0, 0);
        oacc[j] = __builtin_amdgcn_mfma_f32_16x16x32_bf16(pa1, b1, oacc[j], 0, 0, 0);
      }
      __builtin_amdgcn_s_setprio(0);
      __syncthreads();
    }

    #pragma unroll
    for (int j = 0; j < 4; ++j)
      #pragma unroll
      for (int r = 0; r < 4; ++r) {
        int qrow = wave * 16 + kgrp * 4 + r;
        o[base + (size_t)(qt * 64 + qrow) * C_ + j * 16 + rl] = f2b(oacc[j][r] / l_[r]);
      }
  }
}

// ------- MFMA BT GEMM, m97-style staging (VALIDATED r10) -------
// MFAST: m-tile on blockIdx.x. SWZ: 1-D grid + bijective XCD-chunked remap (m204), m fastest.
// EPI: 0 = store bf16, 1 = relu bf16, 2 = fp32 residual +=, 3 = store fp32
template<int BM, int BN, int EPI, bool MFAST, bool SWZ>
__global__ __launch_bounds__(256) void gemm_bt(const unsigned short* __restrict__ A,
                                               const unsigned short* __restrict__ Bt,
                                               const float* __restrict__ bias,
                                               unsigned short* __restrict__ outb,
                                               float* __restrict__ outf,
                                               int M, int N, int K, int ldO,
                                               size_t zBt, size_t zOut, int nMt) {
  constexpr int BK = 32;
  __shared__ __align__(16) unsigned short As[BM * BK];
  __shared__ __align__(16) unsigned short Bs[BN * BK];
  constexpr int FM = BM / 32, FN = BN / 32;

  int tid = threadIdx.x;
  int lane = tid & 63, wave = tid >> 6;
  int wr = wave >> 1, wc = wave & 1;
  int m0, n0;
  if (SWZ) {
    int nwg = gridDim.x, wg = blockIdx.x;
    int qq = nwg >> 3, rr = nwg & 7;
    int xcd = wg & 7, off = wg >> 3;
    int wgid = (xcd < rr ? xcd * (qq + 1) : rr * (qq + 1) + (xcd - rr) * qq) + off;
    m0 = (wgid % nMt) * BM;
    n0 = (wgid / nMt) * BN;
  } else {
    m0 = (MFAST ? blockIdx.x : blockIdx.y) * BM;
    n0 = (MFAST ? blockIdx.y : blockIdx.x) * BN;
  }
  int rl = lane & 15, koff = (lane >> 4) * 8;
  Bt += zBt * blockIdx.z;

  int srow = lane >> 2, sseg = (lane & 3) * 8;

  f32x4 acc[FM][FN] = {};

  for (int k0 = 0; k0 < K; k0 += BK) {
    #pragma unroll
    for (int i = 0; i < BM / 64; ++i) {
      int r = i * 64 + wave * 16;
      gload16(&A[(size_t)(m0 + r + srow) * K + k0 + sseg], &As[r * BK]);
    }
    #pragma unroll
    for (int i = 0; i < BN / 64; ++i) {
      int r = i * 64 + wave * 16;
      gload16(&Bt[(size_t)(n0 + r + srow) * K + k0 + sseg], &Bs[r * BK]);
    }
    __syncthreads();

    short8 af[FM], bfr[FN];
    #pragma unroll
    for (int i = 0; i < FM; ++i)
      af[i] = *(const short8*)&As[(wr * (BM / 2) + i * 16 + rl) * BK + koff];
    #pragma unroll
    for (int j = 0; j < FN; ++j)
      bfr[j] = *(const short8*)&Bs[(wc * (BN / 2) + j * 16 + rl) * BK + koff];
    #pragma unroll
    for (int i = 0; i < FM; ++i)
      #pragma unroll
      for (int j = 0; j < FN; ++j)
        acc[i][j] = __builtin_amdgcn_mfma_f32_16x16x32_bf16(af[i], bfr[j], acc[i][j], 0, 0, 0);
    __syncthreads();
  }

  int rbase = (lane >> 4) * 4;
  #pragma unroll
  for (int i = 0; i < FM; ++i) {
    #pragma unroll
    for (int j = 0; j < FN; ++j) {
      #pragma unroll
      for (int r = 0; r < 4; ++r) {
        int m = m0 + wr * (BM / 2) + i * 16 + rbase + r;
        int n = n0 + wc * (BN / 2) + j * 16 + (lane & 15);
        float val = acc[i][j][r];
        if (bias) val += bias[n];
        if (EPI == 0)      (outb + zOut * blockIdx.z)[(size_t)m * ldO + n] = f2b(val);
        else if (EPI == 1) (outb + zOut * blockIdx.z)[(size_t)m * ldO + n] = f2b(fmaxf(val, 0.f));
        else if (EPI == 2) (outf + zOut * blockIdx.z)[(size_t)m * ldO + n] += val;
        else               (outf + zOut * blockIdx.z)[(size_t)m * ldO + n] = val;
      }
    }
  }
}

// ---------------- host-side launch ----------------
extern "C" void kernel_launch(void* const* d_in, const int* in_sizes, int n_in,
                              void* d_out, int out_size, void* d_ws, size_t ws_size,
                              hipStream_t stream) {
  const int*   idx  = (const int*)d_in[0];
  const float* tok  = (const float*)d_in[1];
  const float* pos  = (const float*)d_in[2];
  const float* Wq   = (const float*)d_in[3];
  const float* Wk   = (const float*)d_in[4];
  const float* Wv   = (const float*)d_in[5];
  const float* Wp   = (const float*)d_in[6];
  const float* bp   = (const float*)d_in[7];
  const float* ln1g = (const float*)d_in[8];
  const float* ln1b = (const float*)d_in[9];
  const float* ln2g = (const float*)d_in[10];
  const float* ln2b = (const float*)d_in[11];
  const float* W1   = (const float*)d_in[12];
  const float* b1   = (const float*)d_in[13];
  const float* W2   = (const float*)d_in[14];
  const float* b2   = (const float*)d_in[15];
  const float* lnfg = (const float*)d_in[16];
  const float* lnfb = (const float*)d_in[17];
  const float* Wh   = (const float*)d_in[18];
  const float* bh   = (const float*)d_in[19];

  float* out = (float*)d_out;   // fp32 logits

  const size_t MC = (size_t)M_ * C_;
  const size_t fixed = MC*4 + MC*2 + MC*2*4;                 // x, h, qkvo region
  const size_t need_chunk = fixed + (size_t)NVC_*C_*2;       // 31.9 MB (proven available)
  const size_t need_full  = fixed + (size_t)V_*C_*2;         // 71.2 MB (runtime-checked)
  if (ws_size < need_chunk) return;
  const bool full_head = (ws_size >= need_full);

  char* p = (char*)d_ws;
  float*          x   = (float*)p;            p += MC*4;
  unsigned short* h   = (unsigned short*)p;   p += MC*2;
  unsigned short* qb  = (unsigned short*)p;   p += MC*2;   // qb,kb,vb contiguous (z-batch)
  unsigned short* kb  = (unsigned short*)p;   p += MC*2;
  unsigned short* vb  = (unsigned short*)p;   p += MC*2;
  unsigned short* ob  = (unsigned short*)p;   p += MC*2;
  unsigned short* WT  = (unsigned short*)p;                // 9.8 MB (chunk) or 49 MB (full)
  unsigned short* mid = qb;                   // [M][C4] bf16, overlays qkvo (dead)

  unsigned short* WqT = WT;                   // WqT,WkT,WvT,WpT contiguous
  unsigned short* WpT = WT + (size_t)3*C_*C_;
  unsigned short* W12T = WT;

  embed_kernel<<<M_, 256, 0, stream>>>(idx, tok, pos, x);

  for (int l = 0; l < L_; ++l) {
    size_t wo  = (size_t)l * C_ * C_;
    size_t wo4 = (size_t)l * C_ * C4_;
    size_t woq = (size_t)l * H_ * C_ * HS_;

    transpose_qkvp<<<dim3(HS_/32, C_/32, 48), 256, 0, stream>>>(Wq + woq, Wk + woq, Wv + woq, Wp + wo, WqT);

    ln_kernel<<<M_, 256, 0, stream>>>(x, ln1g + (size_t)l*C_, ln1b + (size_t)l*C_, h);
    gemm_bt<64,64,0,false,false><<<dim3(C_/64, M_/64, 3), 256, 0, stream>>>(h, WqT, nullptr, qb, nullptr,
                                                                            M_, C_, C_, C_, (size_t)C_*C_, MC, 0);
    attn_mfma<<<dim3(8, B_*H_), 256, 0, stream>>>(qb, kb, vb, ob);
    gemm_bt<64,64,2,false,false><<<dim3(C_/64, M_/64), 256, 0, stream>>>(ob, WpT, bp + (size_t)l*C_, nullptr, x,
                                                                         M_, C_, C_, C_, 0, 0, 0);

    ln_kernel<<<M_, 256, 0, stream>>>(x, ln2g + (size_t)l*C_, ln2b + (size_t)l*C_, h);
    transpose_f2b<<<dim3(C4_/32, C_/32, 1), 256, 0, stream>>>(W1 + wo4, W12T, C4_, C_, 0, 0);
    gemm_bt<128,128,1,true,true><<<dim3((M_/128)*(C4_/128)), 256, 0, stream>>>(h, W12T, b1 + (size_t)l*C4_, mid, nullptr,
                                                                               M_, C4_, C_, C4_, 0, 0, M_/128);
    transpose_f2b<<<dim3(C_/32, C4_/32, 1), 256, 0, stream>>>(W2 + wo4, W12T, C_, C4_, 0, 0);
    gemm_bt<64,64,2,true,true><<<dim3((M_/64)*(C_/64)), 256, 0, stream>>>(mid, W12T, b2 + (size_t)l*C_, nullptr, x,
                                                                          M_, C_, C4_, C_, 0, 0, M_/64);
  }

  // ---- final LN + lm_head (fp32 store) ----
  ln_kernel<<<M_, 256, 0, stream>>>(x, lnfg, lnfb, h);
  if (full_head) {
    transpose_f2b<<<dim3(V_/32, C_/32, 1), 256, 0, stream>>>(Wh, WT, V_, C_, 0, 0);
    gemm_bt<128,128,3,true,true><<<dim3((M_/128)*(V_/128)), 256, 0, stream>>>(
        h, WT, bh, nullptr, out, M_, V_, C_, V_, 0, 0, M_/128);
  } else {
    for (int ci = 0; ci < V_/NVC_; ++ci) {
      transpose_f2b<<<dim3(NVC_/32, C_/32, 1), 256, 0, stream>>>(Wh + (size_t)ci*NVC_, WT, V_, C_, 0, 0);
      gemm_bt<128,128,3,true,true><<<dim3((M_/128)*(NVC_/128)), 256, 0, stream>>>(
          h, WT, bh + (size_t)ci*NVC_, nullptr, out + (size_t)ci*NVC_, M_, NVC_, C_, V_, 0, 0, M_/128);
    }
  }
}

// Round 14
// 1211.502 us; speedup vs baseline: 11.5043x; 1.0810x over previous
//
#include <hip/hip_runtime.h>

// ---------------- problem constants ----------------
#define B_ 2
#define T_ 1024
#define C_ 768
#define H_ 12
#define L_ 6
#define V_ 32000
#define HS_ 64
#define M_ (B_*T_)            // 2048 token rows
#define C4_ (4*C_)            // 3072
#define NVC_ 6400             // lm_head column chunk (fallback path)

typedef __attribute__((ext_vector_type(8))) short short8;
typedef __attribute__((ext_vector_type(4))) float f32x4;

__device__ __forceinline__ float b2f(unsigned short u) {
  union { unsigned int i; float f; } x; x.i = ((unsigned int)u) << 16; return x.f;
}
__device__ __forceinline__ unsigned short f2b(float f) {
  unsigned int u = __builtin_bit_cast(unsigned int, f);
  u += 0x7fffu + ((u >> 16) & 1u);
  return (unsigned short)(u >> 16);
}

// async global->LDS, 16B per lane; LDS dest wave-uniform, lanes write dest + lane*16
__device__ __forceinline__ void gload16(const unsigned short* g, unsigned short* l) {
  __builtin_amdgcn_global_load_lds(
      (const __attribute__((address_space(1))) unsigned int*)g,
      (__attribute__((address_space(3))) unsigned int*)l, 16, 0, 0);
}

// -------- transpose + fp32->bf16: out[c][r] = bf16(in[r][c]), z-batched (VALIDATED) --------
__global__ __launch_bounds__(256) void transpose_f2b(const float* __restrict__ in,
                                                     unsigned short* __restrict__ out,
                                                     int ldi, int ldo, size_t zi, size_t zo) {
  __shared__ unsigned short tile[32][33];
  in  += zi * blockIdx.z;
  out += zo * blockIdx.z;
  int c0 = blockIdx.x * 32, r0 = blockIdx.y * 32;
  int tx = threadIdx.x & 31, ty = threadIdx.x >> 5;   // 32 x 8
  #pragma unroll
  for (int j = 0; j < 32; j += 8)
    tile[ty + j][tx] = f2b(in[(size_t)(r0 + ty + j) * ldi + c0 + tx]);
  __syncthreads();
  #pragma unroll
  for (int j = 0; j < 32; j += 8)
    out[(size_t)(c0 + ty + j) * ldo + r0 + tx] = tile[tx][ty + j];
}

// -------- merged QKV+P transpose: z in [0,48) --------
__global__ __launch_bounds__(256) void transpose_qkvp(const float* __restrict__ Wq,
                                                      const float* __restrict__ Wk,
                                                      const float* __restrict__ Wv,
                                                      const float* __restrict__ Wp,
                                                      unsigned short* __restrict__ out) {
  __shared__ unsigned short tile[32][33];
  int z = blockIdx.z;
  const float* in; unsigned short* o; int ldi; int cbase;
  if (z < 36) {
    int which = z / H_, hh = z % H_;
    in = (which == 0 ? Wq : which == 1 ? Wk : Wv) + (size_t)hh * C_ * HS_;
    o = out + (size_t)which * C_ * C_ + (size_t)hh * HS_ * C_;
    ldi = HS_; cbase = 0;
  } else {
    int ch = z - 36;
    in = Wp; ldi = C_; cbase = ch * 64;
    o = out + (size_t)3 * C_ * C_ + (size_t)ch * 64 * C_;
  }
  int c0 = blockIdx.x * 32, r0 = blockIdx.y * 32;
  int tx = threadIdx.x & 31, ty = threadIdx.x >> 5;
  #pragma unroll
  for (int j = 0; j < 32; j += 8)
    tile[ty + j][tx] = f2b(in[(size_t)(r0 + ty + j) * ldi + cbase + c0 + tx]);
  __syncthreads();
  #pragma unroll
  for (int j = 0; j < 32; j += 8)
    o[(size_t)(c0 + ty + j) * C_ + r0 + tx] = tile[tx][ty + j];
}

// ---------------- embedding ----------------
__global__ __launch_bounds__(256) void embed_kernel(const int* __restrict__ idx,
                                                    const float* __restrict__ tok,
                                                    const float* __restrict__ pos,
                                                    float* __restrict__ x) {
  int m = blockIdx.x;
  int t = m & (T_ - 1);
  int tk = idx[m];
  #pragma unroll
  for (int i = 0; i < 3; ++i) {
    int c = threadIdx.x + i * 256;
    x[(size_t)m * C_ + c] = tok[(size_t)tk * C_ + c] + pos[(size_t)t * C_ + c];
  }
}

// ---------------- layernorm: wave-per-row, no LDS, no barriers ----------------
__global__ __launch_bounds__(256) void ln_kernel(const float* __restrict__ x,
                                                 const float* __restrict__ g,
                                                 const float* __restrict__ bta,
                                                 unsigned short* __restrict__ h) {
  int wave = threadIdx.x >> 6, lane = threadIdx.x & 63;
  int m = blockIdx.x * 4 + wave;
  const float* xr = x + (size_t)m * C_;
  float v[12], s = 0.f, ss = 0.f;
  #pragma unroll
  for (int i = 0; i < 12; ++i) {
    v[i] = xr[lane + i * 64];
    s += v[i]; ss += v[i] * v[i];
  }
  #pragma unroll
  for (int off = 32; off; off >>= 1) { s += __shfl_xor(s, off); ss += __shfl_xor(ss, off); }
  float mean = s * (1.f / C_);
  float var  = fmaxf(ss * (1.f / C_) - mean * mean, 0.f);
  float rstd = rsqrtf(var + 1e-5f);
  #pragma unroll
  for (int i = 0; i < 12; ++i) {
    int c = lane + i * 64;
    h[(size_t)m * C_ + c] = f2b((v[i] - mean) * rstd * g[c] + bta[c]);
  }
}

// ---------------- MFMA flash attention (r12-validated; paired q-tiles) ----------------
__global__ __launch_bounds__(256) void attn_mfma(const unsigned short* __restrict__ q,
                                                 const unsigned short* __restrict__ k,
                                                 const unsigned short* __restrict__ v,
                                                 unsigned short* __restrict__ o) {
  const float scale = 0.03608439182435161f;   // 768^-0.5 (reference scales by C, not HS)
  __shared__ __align__(16) unsigned short Ks[64 * 72];
  __shared__ __align__(16) unsigned short Vt[64 * 72];
  __shared__ __align__(16) unsigned short Ps[4][16 * 72];

  int tid = threadIdx.x;
  int lane = tid & 63, wave = tid >> 6;
  int rl = lane & 15, kgrp = lane >> 4, koff = kgrp * 8;
  int bh = blockIdx.y;
  int hh = bh % H_, bb = bh / H_;
  size_t base = (size_t)bb * T_ * C_ + (size_t)hh * HS_;

  for (int pass = 0; pass < 2; ++pass) {
    int qt = pass ? (15 - (int)blockIdx.x) : (int)blockIdx.x;

    short8 qf0 = *(const short8*)&q[base + (size_t)(qt * 64 + wave * 16 + rl) * C_ + koff];
    short8 qf1 = *(const short8*)&q[base + (size_t)(qt * 64 + wave * 16 + rl) * C_ + 32 + koff];

    float m_[4], l_[4];
    f32x4 oacc[4];
    #pragma unroll
    for (int r = 0; r < 4; ++r) { m_[r] = -INFINITY; l_[r] = 0.f; }
    #pragma unroll
    for (int j = 0; j < 4; ++j) oacc[j] = (f32x4){0.f, 0.f, 0.f, 0.f};

    short8 kreg[2], vreg[2];
    #pragma unroll
    for (int i = 0; i < 2; ++i) {
      int e = tid + i * 256;
      kreg[i] = *(const short8*)&k[base + (size_t)(e >> 3) * C_ + (e & 7) * 8];
      vreg[i] = *(const short8*)&v[base + (size_t)(e >> 3) * C_ + (e & 7) * 8];
    }

    for (int kt = 0; kt <= qt; ++kt) {
      #pragma unroll
      for (int i = 0; i < 2; ++i) {
        int e = tid + i * 256, row = e >> 3, c8 = e & 7;
        *(short8*)&Ks[row * 72 + c8 * 8] = kreg[i];
      }
      #pragma unroll
      for (int i = 0; i < 2; ++i) {
        int e = tid + i * 256, kk = e >> 3, d8 = (e & 7) * 8;
        short8 vv = vreg[i];
        #pragma unroll
        for (int t2 = 0; t2 < 8; ++t2) {
          int ii = (t2 + tid) & 7;
          Vt[(d8 + ii) * 72 + kk] = vv[ii];
        }
      }
      __syncthreads();

      if (kt < qt) {
        #pragma unroll
        for (int i = 0; i < 2; ++i) {
          int e = tid + i * 256;
          kreg[i] = *(const short8*)&k[base + (size_t)((kt + 1) * 64 + (e >> 3)) * C_ + (e & 7) * 8];
          vreg[i] = *(const short8*)&v[base + (size_t)((kt + 1) * 64 + (e >> 3)) * C_ + (e & 7) * 8];
        }
      }

      f32x4 s[4];
      #pragma unroll
      for (int j = 0; j < 4; ++j) s[j] = (f32x4){0.f, 0.f, 0.f, 0.f};
      __builtin_amdgcn_s_setprio(1);
      #pragma unroll
      for (int j = 0; j < 4; ++j) {
        short8 b0 = *(const short8*)&Ks[(j * 16 + rl) * 72 + koff];
        short8 b1 = *(const short8*)&Ks[(j * 16 + rl) * 72 + 32 + koff];
        s[j] = __builtin_amdgcn_mfma_f32_16x16x32_bf16(qf0, b0, s[j], 0, 0, 0);
        s[j] = __builtin_amdgcn_mfma_f32_16x16x32_bf16(qf1, b1, s[j], 0, 0, 0);
      }
      __builtin_amdgcn_s_setprio(0);

      bool diag = (kt == qt);
      #pragma unroll
      for (int j = 0; j < 4; ++j)
        #pragma unroll
        for (int r = 0; r < 4; ++r) {
          float sv = s[j][r] * scale;
          if (diag) {
            int urow = j * 16 + rl, qrow = wave * 16 + kgrp * 4 + r;
            if (urow > qrow) sv = -INFINITY;
          }
          s[j][r] = sv;
        }

      float corr[4], rs[4];
      #pragma unroll
      for (int r = 0; r < 4; ++r) {
        float mrow = fmaxf(fmaxf(s[0][r], s[1][r]), fmaxf(s[2][r], s[3][r]));
        #pragma unroll
        for (int off = 8; off; off >>= 1) mrow = fmaxf(mrow, __shfl_xor(mrow, off));
        float mnew = fmaxf(m_[r], mrow);
        corr[r] = __expf(m_[r] - mnew);
        m_[r] = mnew;
      }
      #pragma unroll
      for (int r = 0; r < 4; ++r) rs[r] = 0.f;
      #pragma unroll
      for (int j = 0; j < 4; ++j)
        #pragma unroll
        for (int r = 0; r < 4; ++r) {
          float p = (s[j][r] == -INFINITY) ? 0.f : __expf(s[j][r] - m_[r]);
          s[j][r] = p;
          rs[r] += p;
        }
      #pragma unroll
      for (int r = 0; r < 4; ++r) {
        #pragma unroll
        for (int off = 8; off; off >>= 1) rs[r] += __shfl_xor(rs[r], off);
        l_[r] = l_[r] * corr[r] + rs[r];
      }
      #pragma unroll
      for (int j = 0; j < 4; ++j)
        #pragma unroll
        for (int r = 0; r < 4; ++r) oacc[j][r] *= corr[r];

      #pragma unroll
      for (int j = 0; j < 4; ++j)
        #pragma unroll
        for (int r = 0; r < 4; ++r)
          Ps[wave][(kgrp * 4 + r) * 72 + j * 16 + rl] = f2b(s[j][r]);

      short8 pa0 = *(const short8*)&Ps[wave][rl * 72 + koff];
      short8 pa1 = *(const short8*)&Ps[wave][rl * 72 + 32 + koff];
      __builtin_amdgcn_s_setprio(1);
      #pragma unroll
      for (int j = 0; j < 4; ++j) {
        short8 b0 = *(const short8*)&Vt[(j * 16 + rl) * 72 + koff];
        short8 b1 = *(const short8*)&Vt[(j * 16 + rl) * 72 + 32 + koff];
        oacc[j] = __builtin_amdgcn_mfma_f32_16x16x32_bf16(pa0, b0, oacc[j], 0, 0, 0);
        oacc[j] = __builtin_amdgcn_mfma_f32_16x16x32_bf16(pa1, b1, oacc[j], 0, 0, 0);
      }
      __builtin_amdgcn_s_setprio(0);
      __syncthreads();
    }

    #pragma unroll
    for (int j = 0; j < 4; ++j)
      #pragma unroll
      for (int r = 0; r < 4; ++r) {
        int qrow = wave * 16 + kgrp * 4 + r;
        o[base + (size_t)(qt * 64 + qrow) * C_ + j * 16 + rl] = f2b(oacc[j][r] / l_[r]);
      }
  }
}

// ------- MFMA BT GEMM: BK=64, XOR-swizzled LDS (chunk c of row r at physical c^(r&7)) -------
// Write side: linear gload16 dest + permuted GLOBAL source chunk (rule #21).
// Read side: ds_read physical chunk (c ^ (rl&7)) -> 2-way bank aliasing (free).
// MFAST: m-tile fastest. SWZ: bijective XCD remap (m204). EPI: 0 bf16, 1 relu bf16, 2 f32 +=, 3 f32
template<int BM, int BN, int EPI, bool MFAST, bool SWZ>
__global__ __launch_bounds__(256) void gemm_bt(const unsigned short* __restrict__ A,
                                               const unsigned short* __restrict__ Bt,
                                               const float* __restrict__ bias,
                                               unsigned short* __restrict__ outb,
                                               float* __restrict__ outf,
                                               int M, int N, int K, int ldO,
                                               size_t zBt, size_t zOut, int nMt) {
  constexpr int BK = 64;
  __shared__ __align__(16) unsigned short As[BM * BK];
  __shared__ __align__(16) unsigned short Bs[BN * BK];
  constexpr int FM = BM / 32, FN = BN / 32;

  int tid = threadIdx.x;
  int lane = tid & 63, wave = tid >> 6;
  int wr = wave >> 1, wc = wave & 1;
  int m0, n0;
  if (SWZ) {
    int nwg = gridDim.x, wg = blockIdx.x;
    int qq = nwg >> 3, rr = nwg & 7;
    int xcd = wg & 7, off = wg >> 3;
    int wgid = (xcd < rr ? xcd * (qq + 1) : rr * (qq + 1) + (xcd - rr) * qq) + off;
    m0 = (wgid % nMt) * BM;
    n0 = (wgid / nMt) * BN;
  } else {
    m0 = (MFAST ? blockIdx.x : blockIdx.y) * BM;
    n0 = (MFAST ? blockIdx.y : blockIdx.x) * BN;
  }
  int rl = lane & 15, kgrp = lane >> 4;
  Bt += zBt * blockIdx.z;

  // staging: one gload16 covers 8 rows of 128B; lane l -> row l>>3, global chunk (l&7)^(l>>3)
  int srow = lane >> 3;
  int scol = ((lane & 7) ^ srow) * 8;

  // read-side physical chunk offsets (elems) for k-low / k-high halves
  int pc0 = ((kgrp)     ^ (rl & 7)) * 8;
  int pc1 = ((4 + kgrp) ^ (rl & 7)) * 8;

  f32x4 acc[FM][FN] = {};

  for (int k0 = 0; k0 < K; k0 += BK) {
    #pragma unroll
    for (int i = 0; i < BM / 32; ++i) {
      int r = i * 32 + wave * 8;             // multiple of 8 (wave-uniform)
      gload16(&A[(size_t)(m0 + r + srow) * K + k0 + scol], &As[r * BK]);
    }
    #pragma unroll
    for (int i = 0; i < BN / 32; ++i) {
      int r = i * 32 + wave * 8;
      gload16(&Bt[(size_t)(n0 + r + srow) * K + k0 + scol], &Bs[r * BK]);
    }
    __syncthreads();   // compiler drains vmcnt before barrier

    short8 af0[FM], af1[FM], bf0[FN], bf1[FN];
    #pragma unroll
    for (int i = 0; i < FM; ++i) {
      int row = wr * (BM / 2) + i * 16 + rl;
      af0[i] = *(const short8*)&As[row * BK + pc0];
      af1[i] = *(const short8*)&As[row * BK + pc1];
    }
    #pragma unroll
    for (int j = 0; j < FN; ++j) {
      int row = wc * (BN / 2) + j * 16 + rl;
      bf0[j] = *(const short8*)&Bs[row * BK + pc0];
      bf1[j] = *(const short8*)&Bs[row * BK + pc1];
    }
    #pragma unroll
    for (int i = 0; i < FM; ++i)
      #pragma unroll
      for (int j = 0; j < FN; ++j) {
        acc[i][j] = __builtin_amdgcn_mfma_f32_16x16x32_bf16(af0[i], bf0[j], acc[i][j], 0, 0, 0);
        acc[i][j] = __builtin_amdgcn_mfma_f32_16x16x32_bf16(af1[i], bf1[j], acc[i][j], 0, 0, 0);
      }
    __syncthreads();
  }

  int rbase = kgrp * 4;
  #pragma unroll
  for (int i = 0; i < FM; ++i) {
    #pragma unroll
    for (int j = 0; j < FN; ++j) {
      #pragma unroll
      for (int r = 0; r < 4; ++r) {
        int m = m0 + wr * (BM / 2) + i * 16 + rbase + r;
        int n = n0 + wc * (BN / 2) + j * 16 + rl;
        float val = acc[i][j][r];
        if (bias) val += bias[n];
        if (EPI == 0)      (outb + zOut * blockIdx.z)[(size_t)m * ldO + n] = f2b(val);
        else if (EPI == 1) (outb + zOut * blockIdx.z)[(size_t)m * ldO + n] = f2b(fmaxf(val, 0.f));
        else if (EPI == 2) (outf + zOut * blockIdx.z)[(size_t)m * ldO + n] += val;
        else               (outf + zOut * blockIdx.z)[(size_t)m * ldO + n] = val;
      }
    }
  }
}

// ---------------- host-side launch ----------------
extern "C" void kernel_launch(void* const* d_in, const int* in_sizes, int n_in,
                              void* d_out, int out_size, void* d_ws, size_t ws_size,
                              hipStream_t stream) {
  const int*   idx  = (const int*)d_in[0];
  const float* tok  = (const float*)d_in[1];
  const float* pos  = (const float*)d_in[2];
  const float* Wq   = (const float*)d_in[3];
  const float* Wk   = (const float*)d_in[4];
  const float* Wv   = (const float*)d_in[5];
  const float* Wp   = (const float*)d_in[6];
  const float* bp   = (const float*)d_in[7];
  const float* ln1g = (const float*)d_in[8];
  const float* ln1b = (const float*)d_in[9];
  const float* ln2g = (const float*)d_in[10];
  const float* ln2b = (const float*)d_in[11];
  const float* W1   = (const float*)d_in[12];
  const float* b1   = (const float*)d_in[13];
  const float* W2   = (const float*)d_in[14];
  const float* b2   = (const float*)d_in[15];
  const float* lnfg = (const float*)d_in[16];
  const float* lnfb = (const float*)d_in[17];
  const float* Wh   = (const float*)d_in[18];
  const float* bh   = (const float*)d_in[19];

  float* out = (float*)d_out;   // fp32 logits

  const size_t MC = (size_t)M_ * C_;
  const size_t fixed = MC*4 + MC*2 + MC*2*4;                 // x, h, qkvo region
  const size_t need_chunk = fixed + (size_t)NVC_*C_*2;       // 31.9 MB (proven available)
  const size_t need_full  = fixed + (size_t)V_*C_*2;         // 71.2 MB (runtime-checked)
  if (ws_size < need_chunk) return;
  const bool full_head = (ws_size >= need_full);

  char* p = (char*)d_ws;
  float*          x   = (float*)p;            p += MC*4;
  unsigned short* h   = (unsigned short*)p;   p += MC*2;
  unsigned short* qb  = (unsigned short*)p;   p += MC*2;   // qb,kb,vb contiguous (z-batch)
  unsigned short* kb  = (unsigned short*)p;   p += MC*2;
  unsigned short* vb  = (unsigned short*)p;   p += MC*2;
  unsigned short* ob  = (unsigned short*)p;   p += MC*2;
  unsigned short* WT  = (unsigned short*)p;                // 9.8 MB (chunk) or 49 MB (full)
  unsigned short* mid = qb;                   // [M][C4] bf16, overlays qkvo (dead)

  unsigned short* WqT = WT;                   // WqT,WkT,WvT,WpT contiguous
  unsigned short* WpT = WT + (size_t)3*C_*C_;
  unsigned short* W12T = WT;

  embed_kernel<<<M_, 256, 0, stream>>>(idx, tok, pos, x);

  for (int l = 0; l < L_; ++l) {
    size_t wo  = (size_t)l * C_ * C_;
    size_t wo4 = (size_t)l * C_ * C4_;
    size_t woq = (size_t)l * H_ * C_ * HS_;

    transpose_qkvp<<<dim3(HS_/32, C_/32, 48), 256, 0, stream>>>(Wq + woq, Wk + woq, Wv + woq, Wp + wo, WqT);

    ln_kernel<<<M_/4, 256, 0, stream>>>(x, ln1g + (size_t)l*C_, ln1b + (size_t)l*C_, h);
    gemm_bt<64,64,0,false,false><<<dim3(C_/64, M_/64, 3), 256, 0, stream>>>(h, WqT, nullptr, qb, nullptr,
                                                                            M_, C_, C_, C_, (size_t)C_*C_, MC, 0);
    attn_mfma<<<dim3(8, B_*H_), 256, 0, stream>>>(qb, kb, vb, ob);
    gemm_bt<64,64,2,false,false><<<dim3(C_/64, M_/64), 256, 0, stream>>>(ob, WpT, bp + (size_t)l*C_, nullptr, x,
                                                                         M_, C_, C_, C_, 0, 0, 0);

    ln_kernel<<<M_/4, 256, 0, stream>>>(x, ln2g + (size_t)l*C_, ln2b + (size_t)l*C_, h);
    transpose_f2b<<<dim3(C4_/32, C_/32, 1), 256, 0, stream>>>(W1 + wo4, W12T, C4_, C_, 0, 0);
    gemm_bt<128,128,1,true,true><<<dim3((M_/128)*(C4_/128)), 256, 0, stream>>>(h, W12T, b1 + (size_t)l*C4_, mid, nullptr,
                                                                               M_, C4_, C_, C4_, 0, 0, M_/128);
    transpose_f2b<<<dim3(C_/32, C4_/32, 1), 256, 0, stream>>>(W2 + wo4, W12T, C_, C4_, 0, 0);
    gemm_bt<64,64,2,true,true><<<dim3((M_/64)*(C_/64)), 256, 0, stream>>>(mid, W12T, b2 + (size_t)l*C_, nullptr, x,
                                                                          M_, C_, C4_, C_, 0, 0, M_/64);
  }

  // ---- final LN + lm_head (fp32 store) ----
  ln_kernel<<<M_/4, 256, 0, stream>>>(x, lnfg, lnfb, h);
  if (full_head) {
    transpose_f2b<<<dim3(V_/32, C_/32, 1), 256, 0, stream>>>(Wh, WT, V_, C_, 0, 0);
    gemm_bt<128,128,3,true,true><<<dim3((M_/128)*(V_/128)), 256, 0, stream>>>(
        h, WT, bh, nullptr, out, M_, V_, C_, V_, 0, 0, M_/128);
  } else {
    for (int ci = 0; ci < V_/NVC_; ++ci) {
      transpose_f2b<<<dim3(NVC_/32, C_/32, 1), 256, 0, stream>>>(Wh + (size_t)ci*NVC_, WT, V_, C_, 0, 0);
      gemm_bt<128,128,3,true,true><<<dim3((M_/128)*(NVC_/128)), 256, 0, stream>>>(
          h, WT, bh + (size_t)ci*NVC_, nullptr, out + (size_t)ci*NVC_, M_, NVC_, C_, V_, 0, 0, M_/128);
    }
  }
}